// Round 18
// baseline (221.799 us; speedup 1.0000x reference)
//
#include <hip/hip_runtime.h>
#include <hip/hip_bf16.h>

#define CIN 512
#define OQK 64
#define NBATCH 4
#define NTOK 4096
#define L2E 1.44269504088896f

typedef float f32x4 __attribute__((ext_vector_type(4)));
typedef _Float16 f16x8 __attribute__((ext_vector_type(8)));
typedef short s16x8 __attribute__((ext_vector_type(8)));
typedef unsigned short u16;
typedef unsigned int u32;
typedef u32 u32x2 __attribute__((ext_vector_type(2)));
typedef u16 u16x4 __attribute__((ext_vector_type(4)));

__device__ inline u16 f2bf(float f) {
    unsigned u = __float_as_uint(f);
    u += 0x7fffu + ((u >> 16) & 1u);
    return (u16)(u >> 16);
}
__device__ inline u16 f2h_bits(float f) {
    _Float16 h = (_Float16)f;
    return __builtin_bit_cast(unsigned short, h);
}
// packed f32x2 -> bf16x2 (RTNE, same bits as f2bf) in ONE VALU op
__device__ inline u32 cvtpk_bf16(float lo, float hi) {
    u32 r;
    asm("v_cvt_pk_bf16_f32 %0, %1, %2" : "=v"(r) : "v"(lo), "v"(hi));
    return r;
}

#define GLOAD16(gp, lp) __builtin_amdgcn_global_load_lds(                        \
    (const __attribute__((address_space(1))) void*)(gp),                         \
    (__attribute__((address_space(3))) void*)(lp), 16, 0, 0)

// ---------------- W f32 -> f16 pre-convert (into P-region alias) ----------------
__global__ __launch_bounds__(256) void wcvt(
    const float* __restrict__ Wq, const float* __restrict__ Wk,
    const float* __restrict__ Wv, u16* __restrict__ Wh)
{
    const size_t e0 = ((size_t)blockIdx.x * 256 + threadIdx.x) * 4;
    if (e0 >= 327680) return;
    const float* src; size_t off;
    if (e0 < 32768)      { src = Wq; off = e0; }
    else if (e0 < 65536) { src = Wk; off = e0 - 32768; }
    else                 { src = Wv; off = e0 - 65536; }
    f32x4 v = *reinterpret_cast<const f32x4*>(src + off);
    u16x4 h;
    #pragma unroll
    for (int j = 0; j < 4; ++j) h[j] = f2h_bits(v[j]);
    *reinterpret_cast<u16x4*>(Wh + e0) = h;
}

// ---------------- fused Q/K/V projections + x_s passthrough (r16-verified) ----------------
__global__ __launch_bounds__(512, 4) void proj_all(
    const float* __restrict__ x,
    const float* __restrict__ bq, const float* __restrict__ bk, const float* __restrict__ bv,
    const u16* __restrict__ Wh,
    u16* __restrict__ Qh, u16* __restrict__ Kh, u16* __restrict__ Vb,
    float* __restrict__ out)
{
    __shared__ u16 Ls[32 * 520];
    __shared__ u16 Lt[32 * 520];

    const int nb = blockIdx.x;   // 128 panels of 32 tokens
    const int b  = blockIdx.y;   // 4
    const int tid = threadIdx.x;
    const int w = tid >> 6, l = tid & 63;
    const int lr = l & 15, lg = l >> 4;
    const int n0 = nb * 32;

    const float* xs = x + (size_t)b * CIN * NTOK;
    const float* xt = x + (size_t)(b + NBATCH) * CIN * NTOK;
    float* os = out + (size_t)b * CIN * NTOK;

    // ---- stage both panels (threads 0-255: x_s + out copy; 256-511: x_t) ----
    {
        const int sg = tid >> 8, st = tid & 255;
        const int q = st & 7, cpb = st >> 3;     // n-quad, channel-pair base
        const float* src = sg ? xt : xs;
        u16* Lp = sg ? Lt : Ls;
        #pragma unroll
        for (int r = 0; r < 8; ++r) {
            const int c0 = (cpb + r * 32) * 2;
            f32x4 va = *reinterpret_cast<const f32x4*>(src + (size_t)c0 * NTOK + n0 + q * 4);
            f32x4 vb = *reinterpret_cast<const f32x4*>(src + (size_t)(c0 + 1) * NTOK + n0 + q * 4);
            if (!sg) {
                *reinterpret_cast<f32x4*>(os + (size_t)c0 * NTOK + n0 + q * 4) = va;
                *reinterpret_cast<f32x4*>(os + (size_t)(c0 + 1) * NTOK + n0 + q * 4) = vb;
            }
            #pragma unroll
            for (int j = 0; j < 4; ++j) {
                u32 pk = (u32)f2h_bits(va[j]) | ((u32)f2h_bits(vb[j]) << 16);
                *reinterpret_cast<u32*>(&Lp[(q * 4 + j) * 520 + c0]) = pk;
            }
        }
    }
    __syncthreads();

    const u16* Wq_ = Wh;
    const u16* Wk_ = Wh + 32768;
    const u16* Wv_ = Wh + 65536;
    const int cb = w * 64;
    const bool isq = (w < 4);
    const int h  = isq ? (w >> 1) : 0;            // Q: token-half
    const int ob = isq ? ((w & 1) * 2) : (w - 4); // Q: o-pair base; K: o-quarter

    f32x4 macc[4][2] = {};   // V accum [cf][fm]  (D[m][c] orientation)
    f32x4 xacc[2] = {};      // Q (i) or K (h2)   (D[o][n] orientation)

    #pragma unroll 4
    for (int t = 0; t < 16; ++t) {
        const int c0 = t * 32 + lg * 8;
        f16x8 X0 = *reinterpret_cast<const f16x8*>(&Lt[lr * 520 + c0]);
        f16x8 X1 = *reinterpret_cast<const f16x8*>(&Lt[(16 + lr) * 520 + c0]);
        #pragma unroll
        for (int cf = 0; cf < 4; ++cf) {
            f16x8 Wvf = *reinterpret_cast<const f16x8*>(&Wv_[(size_t)(cb + cf * 16 + lr) * CIN + c0]);
            macc[cf][0] = __builtin_amdgcn_mfma_f32_16x16x32_f16(X0, Wvf, macc[cf][0], 0, 0, 0);
            macc[cf][1] = __builtin_amdgcn_mfma_f32_16x16x32_f16(X1, Wvf, macc[cf][1], 0, 0, 0);
        }
        if (isq) {
            f16x8 Xs = *reinterpret_cast<const f16x8*>(&Ls[(h * 16 + lr) * 520 + c0]);
            #pragma unroll
            for (int i = 0; i < 2; ++i) {
                f16x8 Wqf = *reinterpret_cast<const f16x8*>(&Wq_[(size_t)((ob + i) * 16 + lr) * CIN + c0]);
                xacc[i] = __builtin_amdgcn_mfma_f32_16x16x32_f16(Wqf, Xs, xacc[i], 0, 0, 0);
            }
        } else {
            f16x8 Wkf = *reinterpret_cast<const f16x8*>(&Wk_[(size_t)(ob * 16 + lr) * CIN + c0]);
            xacc[0] = __builtin_amdgcn_mfma_f32_16x16x32_f16(Wkf, X0, xacc[0], 0, 0, 0);
            xacc[1] = __builtin_amdgcn_mfma_f32_16x16x32_f16(Wkf, X1, xacc[1], 0, 0, 0);
        }
    }

    // ---- V store: packed bf16x4 along m (cvt_pk) ----
    #pragma unroll
    for (int cf = 0; cf < 4; ++cf) {
        const int c = cb + cf * 16 + lr;
        const float bvc = bv[c];
        #pragma unroll
        for (int fm = 0; fm < 2; ++fm) {
            u32x2 pk;
            pk[0] = cvtpk_bf16(macc[cf][fm][0] + bvc, macc[cf][fm][1] + bvc);
            pk[1] = cvtpk_bf16(macc[cf][fm][2] + bvc, macc[cf][fm][3] + bvc);
            *reinterpret_cast<u32x2*>(&Vb[((size_t)b * CIN + c) * NTOK + n0 + fm * 16 + lg * 4]) = pk;
        }
    }
    // ---- Q / K store: packed f16x4 along o.  Q scaled by log2(e). ----
    if (isq) {
        #pragma unroll
        for (int i = 0; i < 2; ++i) {
            u16x4 pk;
            #pragma unroll
            for (int r = 0; r < 4; ++r)
                pk[r] = f2h_bits((xacc[i][r] + bq[(ob + i) * 16 + lg * 4 + r]) * L2E);
            *reinterpret_cast<u16x4*>(&Qh[((size_t)b * NTOK + n0 + h * 16 + lr) * OQK + (ob + i) * 16 + lg * 4]) = pk;
        }
    } else {
        #pragma unroll
        for (int h2 = 0; h2 < 2; ++h2) {
            u16x4 pk;
            #pragma unroll
            for (int r = 0; r < 4; ++r) pk[r] = f2h_bits(xacc[h2][r] + bk[ob * 16 + lg * 4 + r]);
            *reinterpret_cast<u16x4*>(&Kh[((size_t)b * NTOK + n0 + h2 * 16 + lr) * OQK + ob * 16 + lg * 4]) = pk;
        }
    }
}

// ---------------- pass S: P = exp2(K Q'^T) (bf16) + exact den (r16-verified) ----------------

#define SLOADK(mt, KF)                                                          \
  { _Pragma("unroll")                                                           \
    for (int mf_ = 0; mf_ < 4; ++mf_) {                                         \
      const u16* kp = Kbase + (size_t)((mt) * 64 + mf_ * 16 + lr) * OQK + lg * 8; \
      KF[mf_][0] = *reinterpret_cast<const f16x8*>(kp);                         \
      KF[mf_][1] = *reinterpret_cast<const f16x8*>(kp + 32);                    \
    } }

#define STILE(mt, KF)                                                           \
  { _Pragma("unroll")                                                           \
    for (int mf_ = 0; mf_ < 4; ++mf_) {                                         \
      f32x4 s_ = {};                                                            \
      s_ = __builtin_amdgcn_mfma_f32_16x16x32_f16(KF[mf_][0], Bq0, s_, 0, 0, 0);\
      s_ = __builtin_amdgcn_mfma_f32_16x16x32_f16(KF[mf_][1], Bq1, s_, 0, 0, 0);\
      float p0 = exp2f(s_[0]), p1 = exp2f(s_[1]);                               \
      float p2 = exp2f(s_[2]), p3 = exp2f(s_[3]);                               \
      denl += (p0 + p1) + (p2 + p3);                                            \
      u32x2 pk;                                                                 \
      pk[0] = cvtpk_bf16(p0, p1);                                               \
      pk[1] = cvtpk_bf16(p2, p3);                                               \
      const int widx_ = (lr * 64 + mf_ * 16 + lg * 4) ^ ((lr & 7) << 3);        \
      *reinterpret_cast<u32x2*>(&Tw[widx_]) = pk;                               \
    }                                                                           \
    _Pragma("unroll")                                                           \
    for (int rr_ = 0; rr_ < 2; ++rr_) {                                         \
      const int nl_ = (l >> 3) + rr_ * 8;                                       \
      const int ridx_ = (nl_ * 64 + (l & 7) * 8) ^ ((nl_ & 7) << 3);            \
      s16x8 v_ = *reinterpret_cast<const s16x8*>(&Tw[ridx_]);                   \
      *reinterpret_cast<s16x8*>(&Pp[(size_t)(grp * 16 + nl_) * NTOK + (mt) * 64 + (l & 7) * 8]) = v_; \
    } }

__global__ __launch_bounds__(256, 4) void qk_exp(
    const u16* __restrict__ Qh, const u16* __restrict__ Kh,
    u16* __restrict__ P, float* __restrict__ den)
{
    __shared__ float dpart[4][16];
    __shared__ u16 T[4][1024];                     // per-wave 16x64 transpose tile
    const int g = blockIdx.x;
    const int xcd = g & 7;
    const int b = xcd >> 1;
    const int grp = ((g >> 3) << 1) | (xcd & 1);   // 16-row group (0..255)

    const int tid = threadIdx.x;
    const int w = tid >> 6, l = tid & 63;
    const int lr = l & 15, lg = l >> 4;

    const int n = grp * 16 + lr;
    const int mbase = w * 1024;                    // wave's m-quarter
    const u16* Kbase = Kh + ((size_t)b * NTOK + mbase) * OQK;
    u16* Pp = P + (size_t)b * NTOK * NTOK + mbase;
    u16* Tw = T[w];

    f16x8 Bq0, Bq1;
    {
        const u16* qp = Qh + ((size_t)b * NTOK + n) * OQK + lg * 8;
        Bq0 = *reinterpret_cast<const f16x8*>(qp);
        Bq1 = *reinterpret_cast<const f16x8*>(qp + 32);
    }

    float denl = 0.f;
    f16x8 KfA[4][2], KfB[4][2];

    SLOADK(0, KfA);
    for (int mt = 0; mt < 16; mt += 2) {
        SLOADK(mt + 1, KfB);
        STILE(mt, KfA);
        if (mt + 2 < 16) SLOADK(mt + 2, KfA);
        STILE(mt + 1, KfB);
    }

    denl += __shfl_xor(denl, 16);
    denl += __shfl_xor(denl, 32);
    if (l < 16) dpart[w][l] = denl;
    __syncthreads();
    if (tid < 16)
        den[(size_t)b * NTOK + grp * 16 + tid] =
            (dpart[0][tid] + dpart[1][tid]) + (dpart[2][tid] + dpart[3][tid]);
}

// ---------------- pass PV: out = x_t + (V P^T) / den ----------------
// 128x128 tile. NEW (r18): 8 waves/block (512 thr) -> 16 waves/CU at the same
// 2 blocks/CU (LDS 64KB x2 = 128KB). Wave = 64c x 32n (8 MFMA/body). Staging:
// 2 GLOAD16/thread/stage; 3-deep prefetch, stage-after-barrier, counted
// vmcnt(4) steady (tail 4/2/0 by FIFO arithmetic). Swizzle + XCD map r14.

#define PVSTAGE(BUF, m0)                                                        \
  { { const int chunk_ = tid;                                                   \
      const int row_ = chunk_ >> 2;                                             \
      const int sl_ = (chunk_ & 3) ^ ((row_ >> 1) & 3);                         \
      GLOAD16(Abase + (size_t)row_ * NTOK + (m0) + sl_ * 8,                     \
              &AS[(BUF) * 4096 + chunk_ * 8]); }                                \
    { const int chunk_ = tid;                                                   \
      const int row_ = chunk_ >> 2;                                             \
      const int sl_ = (chunk_ & 3) ^ ((row_ >> 1) & 3);                         \
      GLOAD16(Bbase + (size_t)row_ * NTOK + (m0) + sl_ * 8,                     \
              &BS[(BUF) * 4096 + chunk_ * 8]); } }

#define PVBODY(CUR, kt, DOSTAGE, VM)                                            \
  {                                                                             \
    asm volatile("s_waitcnt vmcnt(" VM ")" ::: "memory");                       \
    __builtin_amdgcn_s_barrier();                                               \
    if (DOSTAGE) PVSTAGE(((kt) + 3) & 3, ((kt) + 3) * 32);                      \
    s16x8 Af[4], Bf[2];                                                         \
    const int swz_ = ((lr >> 1) & 3) << 3;                                      \
    _Pragma("unroll")                                                           \
    for (int f_ = 0; f_ < 4; ++f_)                                              \
      Af[f_] = *(const s16x8*)&AS[(CUR) * 4096 + (wr * 64 + f_ * 16 + lr) * 32 + ((lg * 8) ^ swz_)]; \
    _Pragma("unroll")                                                           \
    for (int f_ = 0; f_ < 2; ++f_)                                              \
      Bf[f_] = *(const s16x8*)&BS[(CUR) * 4096 + (wc * 32 + f_ * 16 + lr) * 32 + ((lg * 8) ^ swz_)]; \
    __builtin_amdgcn_s_setprio(1);                                              \
    _Pragma("unroll")                                                           \
    for (int cf_ = 0; cf_ < 4; ++cf_)                                           \
      _Pragma("unroll")                                                         \
      for (int nf_ = 0; nf_ < 2; ++nf_)                                         \
        acc[cf_][nf_] = __builtin_amdgcn_mfma_f32_16x16x32_bf16(Af[cf_], Bf[nf_], acc[cf_][nf_], 0, 0, 0); \
    __builtin_amdgcn_s_setprio(0);                                              \
  }

__global__ __launch_bounds__(512, 4) void pv(
    const float* __restrict__ x, const u16* __restrict__ Vb,
    const u16* __restrict__ P, const float* __restrict__ den,
    float* __restrict__ out)
{
    __shared__ u16 AS[4 * 4096];   // 4 bufs x 128rows x 32k  (V)  32 KB
    __shared__ u16 BS[4 * 4096];   // 4 bufs x 128rows x 32k  (P)  32 KB

    const int g = blockIdx.x;
    const int xcd = g & 7;
    const int b = xcd >> 1;
    const int idx = ((g >> 3) << 1) | (xcd & 1);  // 0..127 per batch
    const int bm = (idx >> 1) & 3;                // c-tile: sharers same XCD
    const int bn = ((idx >> 3) << 1) | (idx & 1); // n-tile 0..31

    const int tid = threadIdx.x;
    const int w = tid >> 6, l = tid & 63;
    const int lr = l & 15, lg = l >> 4;
    const int wr = w >> 2, wc = w & 3;            // wave: 64c x 32n

    const u16* Abase = Vb + (size_t)b * CIN * NTOK + (size_t)(bm * 128) * NTOK;
    const u16* Bbase = P + (size_t)b * NTOK * NTOK + (size_t)(bn * 128) * NTOK;

    f32x4 acc[4][2] = {};                         // [cf][nf]

    PVSTAGE(0, 0);
    PVSTAGE(1, 32);
    PVSTAGE(2, 64);
    for (int kt2 = 0; kt2 < 124; kt2 += 4) {
        PVBODY(0, kt2 + 0, true, "4");
        PVBODY(1, kt2 + 1, true, "4");
        PVBODY(2, kt2 + 2, true, "4");
        PVBODY(3, kt2 + 3, true, "4");
    }
    PVBODY(0, 124, true,  "4");
    PVBODY(1, 125, false, "4");
    PVBODY(2, 126, false, "2");
    PVBODY(3, 127, false, "0");

    // epilogue: out = x_t + acc / den[n]
    const float* denb = den + (size_t)b * NTOK;
    float inv[2];
    #pragma unroll
    for (int nf = 0; nf < 2; ++nf) inv[nf] = 1.0f / denb[bn * 128 + wc * 32 + nf * 16 + lr];

    const float* xtp = x + (size_t)(b + NBATCH) * CIN * NTOK;
    float* op = out + (size_t)(b + NBATCH) * CIN * NTOK;
    #pragma unroll
    for (int cf = 0; cf < 4; ++cf) {
        #pragma unroll
        for (int nf = 0; nf < 2; ++nf) {
            #pragma unroll
            for (int r = 0; r < 4; ++r) {
                const int c = bm * 128 + wr * 64 + cf * 16 + lg * 4 + r;
                const int n = bn * 128 + wc * 32 + nf * 16 + lr;
                const size_t idx2 = (size_t)c * NTOK + n;
                op[idx2] = xtp[idx2] + acc[cf][nf][r] * inv[nf];
            }
        }
    }
}

extern "C" void kernel_launch(void* const* d_in, const int* in_sizes, int n_in,
                              void* d_out, int out_size, void* d_ws, size_t ws_size,
                              hipStream_t stream)
{
    (void)in_sizes; (void)n_in; (void)out_size; (void)ws_size;
    const float* x  = (const float*)d_in[0];
    const float* Wq = (const float*)d_in[1];
    const float* bq = (const float*)d_in[2];
    const float* Wk = (const float*)d_in[3];
    const float* bk = (const float*)d_in[4];
    const float* Wv = (const float*)d_in[5];
    const float* bv = (const float*)d_in[6];
    float* out = (float*)d_out;

    // ws layout (~148.1 MB): Qh 2MB | Kh 2MB | Vb 16MB | den 64KB | P 128MB
    // Wh (f16 weights, 640KB) aliases the head of P (dead before qk_exp writes P).
    u16* Qh = (u16*)d_ws;
    u16* Kh = Qh + (size_t)NBATCH * NTOK * OQK;
    u16* Vb = Kh + (size_t)NBATCH * NTOK * OQK;
    float* den = (float*)(Vb + (size_t)NBATCH * CIN * NTOK);
    u16* P  = (u16*)(den + (size_t)NBATCH * NTOK);
    u16* Wh = P;

    wcvt    <<<320, 256, 0, stream>>>(Wq, Wk, Wv, Wh);
    proj_all<<<dim3(128, NBATCH), 512, 0, stream>>>(x, bq, bk, bv, Wh, Qh, Kh, Vb, out);
    qk_exp  <<<1024, 256, 0, stream>>>(Qh, Kh, P, den);
    pv      <<<512, 512, 0, stream>>>(x, Vb, P, den, out);
}

// Round 19
// 210.972 us; speedup vs baseline: 1.0513x; 1.0513x over previous
//
#include <hip/hip_runtime.h>
#include <hip/hip_bf16.h>

#define CIN 512
#define OQK 64
#define NBATCH 4
#define NTOK 4096
#define L2E 1.44269504088896f

typedef float f32x4 __attribute__((ext_vector_type(4)));
typedef _Float16 f16x8 __attribute__((ext_vector_type(8)));
typedef short s16x8 __attribute__((ext_vector_type(8)));
typedef unsigned short u16;
typedef unsigned int u32;
typedef u32 u32x2 __attribute__((ext_vector_type(2)));
typedef u16 u16x4 __attribute__((ext_vector_type(4)));

__device__ inline u16 f2bf(float f) {
    unsigned u = __float_as_uint(f);
    u += 0x7fffu + ((u >> 16) & 1u);
    return (u16)(u >> 16);
}
__device__ inline u16 f2h_bits(float f) {
    _Float16 h = (_Float16)f;
    return __builtin_bit_cast(unsigned short, h);
}
// packed f32x2 -> bf16x2 (RTNE, same bits as f2bf) in ONE VALU op
__device__ inline u32 cvtpk_bf16(float lo, float hi) {
    u32 r;
    asm("v_cvt_pk_bf16_f32 %0, %1, %2" : "=v"(r) : "v"(lo), "v"(hi));
    return r;
}

#define GLOAD16(gp, lp) __builtin_amdgcn_global_load_lds(                        \
    (const __attribute__((address_space(1))) void*)(gp),                         \
    (__attribute__((address_space(3))) void*)(lp), 16, 0, 0)

// ---------------- W f32 -> f16 pre-convert (into P-region alias) ----------------
__global__ __launch_bounds__(256) void wcvt(
    const float* __restrict__ Wq, const float* __restrict__ Wk,
    const float* __restrict__ Wv, u16* __restrict__ Wh)
{
    const size_t e0 = ((size_t)blockIdx.x * 256 + threadIdx.x) * 4;
    if (e0 >= 327680) return;
    const float* src; size_t off;
    if (e0 < 32768)      { src = Wq; off = e0; }
    else if (e0 < 65536) { src = Wk; off = e0 - 32768; }
    else                 { src = Wv; off = e0 - 65536; }
    f32x4 v = *reinterpret_cast<const f32x4*>(src + off);
    u16x4 h;
    #pragma unroll
    for (int j = 0; j < 4; ++j) h[j] = f2h_bits(v[j]);
    *reinterpret_cast<u16x4*>(Wh + e0) = h;
}

// ---------------- fused Q/K/V projections + x_s passthrough (r16-verified) ----------------
__global__ __launch_bounds__(512, 4) void proj_all(
    const float* __restrict__ x,
    const float* __restrict__ bq, const float* __restrict__ bk, const float* __restrict__ bv,
    const u16* __restrict__ Wh,
    u16* __restrict__ Qh, u16* __restrict__ Kh, u16* __restrict__ Vb,
    float* __restrict__ out)
{
    __shared__ u16 Ls[32 * 520];
    __shared__ u16 Lt[32 * 520];

    const int nb = blockIdx.x;   // 128 panels of 32 tokens
    const int b  = blockIdx.y;   // 4
    const int tid = threadIdx.x;
    const int w = tid >> 6, l = tid & 63;
    const int lr = l & 15, lg = l >> 4;
    const int n0 = nb * 32;

    const float* xs = x + (size_t)b * CIN * NTOK;
    const float* xt = x + (size_t)(b + NBATCH) * CIN * NTOK;
    float* os = out + (size_t)b * CIN * NTOK;

    // ---- stage both panels (threads 0-255: x_s + out copy; 256-511: x_t) ----
    {
        const int sg = tid >> 8, st = tid & 255;
        const int q = st & 7, cpb = st >> 3;     // n-quad, channel-pair base
        const float* src = sg ? xt : xs;
        u16* Lp = sg ? Lt : Ls;
        #pragma unroll
        for (int r = 0; r < 8; ++r) {
            const int c0 = (cpb + r * 32) * 2;
            f32x4 va = *reinterpret_cast<const f32x4*>(src + (size_t)c0 * NTOK + n0 + q * 4);
            f32x4 vb = *reinterpret_cast<const f32x4*>(src + (size_t)(c0 + 1) * NTOK + n0 + q * 4);
            if (!sg) {
                *reinterpret_cast<f32x4*>(os + (size_t)c0 * NTOK + n0 + q * 4) = va;
                *reinterpret_cast<f32x4*>(os + (size_t)(c0 + 1) * NTOK + n0 + q * 4) = vb;
            }
            #pragma unroll
            for (int j = 0; j < 4; ++j) {
                u32 pk = (u32)f2h_bits(va[j]) | ((u32)f2h_bits(vb[j]) << 16);
                *reinterpret_cast<u32*>(&Lp[(q * 4 + j) * 520 + c0]) = pk;
            }
        }
    }
    __syncthreads();

    const u16* Wq_ = Wh;
    const u16* Wk_ = Wh + 32768;
    const u16* Wv_ = Wh + 65536;
    const int cb = w * 64;
    const bool isq = (w < 4);
    const int h  = isq ? (w >> 1) : 0;            // Q: token-half
    const int ob = isq ? ((w & 1) * 2) : (w - 4); // Q: o-pair base; K: o-quarter

    f32x4 macc[4][2] = {};   // V accum [cf][fm]  (D[m][c] orientation)
    f32x4 xacc[2] = {};      // Q (i) or K (h2)   (D[o][n] orientation)

    #pragma unroll 4
    for (int t = 0; t < 16; ++t) {
        const int c0 = t * 32 + lg * 8;
        f16x8 X0 = *reinterpret_cast<const f16x8*>(&Lt[lr * 520 + c0]);
        f16x8 X1 = *reinterpret_cast<const f16x8*>(&Lt[(16 + lr) * 520 + c0]);
        #pragma unroll
        for (int cf = 0; cf < 4; ++cf) {
            f16x8 Wvf = *reinterpret_cast<const f16x8*>(&Wv_[(size_t)(cb + cf * 16 + lr) * CIN + c0]);
            macc[cf][0] = __builtin_amdgcn_mfma_f32_16x16x32_f16(X0, Wvf, macc[cf][0], 0, 0, 0);
            macc[cf][1] = __builtin_amdgcn_mfma_f32_16x16x32_f16(X1, Wvf, macc[cf][1], 0, 0, 0);
        }
        if (isq) {
            f16x8 Xs = *reinterpret_cast<const f16x8*>(&Ls[(h * 16 + lr) * 520 + c0]);
            #pragma unroll
            for (int i = 0; i < 2; ++i) {
                f16x8 Wqf = *reinterpret_cast<const f16x8*>(&Wq_[(size_t)((ob + i) * 16 + lr) * CIN + c0]);
                xacc[i] = __builtin_amdgcn_mfma_f32_16x16x32_f16(Wqf, Xs, xacc[i], 0, 0, 0);
            }
        } else {
            f16x8 Wkf = *reinterpret_cast<const f16x8*>(&Wk_[(size_t)(ob * 16 + lr) * CIN + c0]);
            xacc[0] = __builtin_amdgcn_mfma_f32_16x16x32_f16(Wkf, X0, xacc[0], 0, 0, 0);
            xacc[1] = __builtin_amdgcn_mfma_f32_16x16x32_f16(Wkf, X1, xacc[1], 0, 0, 0);
        }
    }

    // ---- V store: packed bf16x4 along m (cvt_pk) ----
    #pragma unroll
    for (int cf = 0; cf < 4; ++cf) {
        const int c = cb + cf * 16 + lr;
        const float bvc = bv[c];
        #pragma unroll
        for (int fm = 0; fm < 2; ++fm) {
            u32x2 pk;
            pk[0] = cvtpk_bf16(macc[cf][fm][0] + bvc, macc[cf][fm][1] + bvc);
            pk[1] = cvtpk_bf16(macc[cf][fm][2] + bvc, macc[cf][fm][3] + bvc);
            *reinterpret_cast<u32x2*>(&Vb[((size_t)b * CIN + c) * NTOK + n0 + fm * 16 + lg * 4]) = pk;
        }
    }
    // ---- Q / K store: packed f16x4 along o.  Q scaled by log2(e). ----
    if (isq) {
        #pragma unroll
        for (int i = 0; i < 2; ++i) {
            u16x4 pk;
            #pragma unroll
            for (int r = 0; r < 4; ++r)
                pk[r] = f2h_bits((xacc[i][r] + bq[(ob + i) * 16 + lg * 4 + r]) * L2E);
            *reinterpret_cast<u16x4*>(&Qh[((size_t)b * NTOK + n0 + h * 16 + lr) * OQK + (ob + i) * 16 + lg * 4]) = pk;
        }
    } else {
        #pragma unroll
        for (int h2 = 0; h2 < 2; ++h2) {
            u16x4 pk;
            #pragma unroll
            for (int r = 0; r < 4; ++r) pk[r] = f2h_bits(xacc[h2][r] + bk[ob * 16 + lg * 4 + r]);
            *reinterpret_cast<u16x4*>(&Kh[((size_t)b * NTOK + n0 + h2 * 16 + lr) * OQK + ob * 16 + lg * 4]) = pk;
        }
    }
}

// ---------------- pass S: P = exp2(K Q'^T) (bf16) + exact den (r16-verified) ----------------

#define SLOADK(mt, KF)                                                          \
  { _Pragma("unroll")                                                           \
    for (int mf_ = 0; mf_ < 4; ++mf_) {                                         \
      const u16* kp = Kbase + (size_t)((mt) * 64 + mf_ * 16 + lr) * OQK + lg * 8; \
      KF[mf_][0] = *reinterpret_cast<const f16x8*>(kp);                         \
      KF[mf_][1] = *reinterpret_cast<const f16x8*>(kp + 32);                    \
    } }

#define STILE(mt, KF)                                                           \
  { _Pragma("unroll")                                                           \
    for (int mf_ = 0; mf_ < 4; ++mf_) {                                         \
      f32x4 s_ = {};                                                            \
      s_ = __builtin_amdgcn_mfma_f32_16x16x32_f16(KF[mf_][0], Bq0, s_, 0, 0, 0);\
      s_ = __builtin_amdgcn_mfma_f32_16x16x32_f16(KF[mf_][1], Bq1, s_, 0, 0, 0);\
      float p0 = exp2f(s_[0]), p1 = exp2f(s_[1]);                               \
      float p2 = exp2f(s_[2]), p3 = exp2f(s_[3]);                               \
      denl += (p0 + p1) + (p2 + p3);                                            \
      u32x2 pk;                                                                 \
      pk[0] = cvtpk_bf16(p0, p1);                                               \
      pk[1] = cvtpk_bf16(p2, p3);                                               \
      const int widx_ = (lr * 64 + mf_ * 16 + lg * 4) ^ ((lr & 7) << 3);        \
      *reinterpret_cast<u32x2*>(&Tw[widx_]) = pk;                               \
    }                                                                           \
    _Pragma("unroll")                                                           \
    for (int rr_ = 0; rr_ < 2; ++rr_) {                                         \
      const int nl_ = (l >> 3) + rr_ * 8;                                       \
      const int ridx_ = (nl_ * 64 + (l & 7) * 8) ^ ((nl_ & 7) << 3);            \
      s16x8 v_ = *reinterpret_cast<const s16x8*>(&Tw[ridx_]);                   \
      *reinterpret_cast<s16x8*>(&Pp[(size_t)(grp * 16 + nl_) * NTOK + (mt) * 64 + (l & 7) * 8]) = v_; \
    } }

__global__ __launch_bounds__(256, 4) void qk_exp(
    const u16* __restrict__ Qh, const u16* __restrict__ Kh,
    u16* __restrict__ P, float* __restrict__ den)
{
    __shared__ float dpart[4][16];
    __shared__ u16 T[4][1024];                     // per-wave 16x64 transpose tile
    const int g = blockIdx.x;
    const int xcd = g & 7;
    const int b = xcd >> 1;
    const int grp = ((g >> 3) << 1) | (xcd & 1);   // 16-row group (0..255)

    const int tid = threadIdx.x;
    const int w = tid >> 6, l = tid & 63;
    const int lr = l & 15, lg = l >> 4;

    const int n = grp * 16 + lr;
    const int mbase = w * 1024;                    // wave's m-quarter
    const u16* Kbase = Kh + ((size_t)b * NTOK + mbase) * OQK;
    u16* Pp = P + (size_t)b * NTOK * NTOK + mbase;
    u16* Tw = T[w];

    f16x8 Bq0, Bq1;
    {
        const u16* qp = Qh + ((size_t)b * NTOK + n) * OQK + lg * 8;
        Bq0 = *reinterpret_cast<const f16x8*>(qp);
        Bq1 = *reinterpret_cast<const f16x8*>(qp + 32);
    }

    float denl = 0.f;
    f16x8 KfA[4][2], KfB[4][2];

    SLOADK(0, KfA);
    for (int mt = 0; mt < 16; mt += 2) {
        SLOADK(mt + 1, KfB);
        STILE(mt, KfA);
        if (mt + 2 < 16) SLOADK(mt + 2, KfA);
        STILE(mt + 1, KfB);
    }

    denl += __shfl_xor(denl, 16);
    denl += __shfl_xor(denl, 32);
    if (l < 16) dpart[w][l] = denl;
    __syncthreads();
    if (tid < 16)
        den[(size_t)b * NTOK + grp * 16 + tid] =
            (dpart[0][tid] + dpart[1][tid]) + (dpart[2][tid] + dpart[3][tid]);
}

// ---------------- pass PV: out = x_t + (V P^T) / den ----------------
// NEW (r19): BK=64 -- 64 K-tiles instead of 128 bodies (wait-points halved,
// 2x MFMA per barrier window). 512 thr (8 waves, wave = 64c x 32n, 16 MFMA +
// 12 ds_read_b128 per tile). 2 bufs x 32KB = 64KB LDS -> 2 blocks/CU =
// 16 waves/CU. Stage(kt+2) after 2nd barrier; steady vmcnt(4), tail 4/0.
// Swizzle for 128B-pitch rows: slot ^= row&7 (involution; disjoint bank-quads).
// XCD P-sharing map unchanged (r14-verified).

#define PVSTAGE(BUF, m0)                                                        \
  { _Pragma("unroll")                                                           \
    for (int i_ = 0; i_ < 2; ++i_) {                                            \
      const int chunk_ = i_ * 512 + tid;                                        \
      const int row_ = chunk_ >> 3;                                             \
      const int sl_ = (chunk_ & 7) ^ (row_ & 7);                                \
      GLOAD16(Abase + (size_t)row_ * NTOK + (m0) + sl_ * 8,                     \
              &AS[(BUF) * 8192 + chunk_ * 8]);                                  \
    }                                                                           \
    _Pragma("unroll")                                                           \
    for (int j_ = 0; j_ < 2; ++j_) {                                            \
      const int chunk_ = j_ * 512 + tid;                                        \
      const int row_ = chunk_ >> 3;                                             \
      const int sl_ = (chunk_ & 7) ^ (row_ & 7);                                \
      GLOAD16(Bbase + (size_t)row_ * NTOK + (m0) + sl_ * 8,                     \
              &BS[(BUF) * 8192 + chunk_ * 8]);                                  \
    } }

#define PVBODY(CUR, kt, DOSTAGE, VM)                                            \
  {                                                                             \
    asm volatile("s_waitcnt vmcnt(" VM ")" ::: "memory");                       \
    __builtin_amdgcn_s_barrier();                                               \
    s16x8 Af[4][2], Bf[2][2];                                                   \
    _Pragma("unroll")                                                           \
    for (int cf_ = 0; cf_ < 4; ++cf_) {                                         \
      const int r_ = wr * 64 + cf_ * 16 + lr;                                   \
      _Pragma("unroll")                                                         \
      for (int kk_ = 0; kk_ < 2; ++kk_) {                                       \
        const int s_ = (kk_ * 4 + lg) ^ (r_ & 7);                               \
        Af[cf_][kk_] = *(const s16x8*)&AS[(CUR) * 8192 + r_ * 64 + s_ * 8];     \
      } }                                                                       \
    _Pragma("unroll")                                                           \
    for (int nf_ = 0; nf_ < 2; ++nf_) {                                         \
      const int r_ = wc * 32 + nf_ * 16 + lr;                                   \
      _Pragma("unroll")                                                         \
      for (int kk_ = 0; kk_ < 2; ++kk_) {                                       \
        const int s_ = (kk_ * 4 + lg) ^ (r_ & 7);                               \
        Bf[nf_][kk_] = *(const s16x8*)&BS[(CUR) * 8192 + r_ * 64 + s_ * 8];     \
      } }                                                                       \
    __builtin_amdgcn_s_setprio(1);                                              \
    _Pragma("unroll")                                                           \
    for (int cf_ = 0; cf_ < 4; ++cf_)                                           \
      _Pragma("unroll")                                                         \
      for (int nf_ = 0; nf_ < 2; ++nf_)                                         \
        acc[cf_][nf_] = __builtin_amdgcn_mfma_f32_16x16x32_bf16(Af[cf_][0], Bf[nf_][0], acc[cf_][nf_], 0, 0, 0); \
    _Pragma("unroll")                                                           \
    for (int cf_ = 0; cf_ < 4; ++cf_)                                           \
      _Pragma("unroll")                                                         \
      for (int nf_ = 0; nf_ < 2; ++nf_)                                         \
        acc[cf_][nf_] = __builtin_amdgcn_mfma_f32_16x16x32_bf16(Af[cf_][1], Bf[nf_][1], acc[cf_][nf_], 0, 0, 0); \
    __builtin_amdgcn_s_setprio(0);                                              \
    __builtin_amdgcn_s_barrier();                                               \
    if (DOSTAGE) PVSTAGE(CUR, ((kt) + 2) * 64);                                 \
  }

__global__ __launch_bounds__(512, 2) void pv(
    const float* __restrict__ x, const u16* __restrict__ Vb,
    const u16* __restrict__ P, const float* __restrict__ den,
    float* __restrict__ out)
{
    __shared__ u16 AS[2 * 8192];   // 2 bufs x 128rows x 64k  (V)  32 KB
    __shared__ u16 BS[2 * 8192];   // 2 bufs x 128rows x 64k  (P)  32 KB

    const int g = blockIdx.x;
    const int xcd = g & 7;
    const int b = xcd >> 1;
    const int idx = ((g >> 3) << 1) | (xcd & 1);  // 0..127 per batch
    const int bm = (idx >> 1) & 3;                // c-tile: sharers same XCD
    const int bn = ((idx >> 3) << 1) | (idx & 1); // n-tile 0..31

    const int tid = threadIdx.x;
    const int w = tid >> 6, l = tid & 63;
    const int lr = l & 15, lg = l >> 4;
    const int wr = w >> 2, wc = w & 3;            // wave: 64c x 32n

    const u16* Abase = Vb + (size_t)b * CIN * NTOK + (size_t)(bm * 128) * NTOK;
    const u16* Bbase = P + (size_t)b * NTOK * NTOK + (size_t)(bn * 128) * NTOK;

    f32x4 acc[4][2] = {};                         // [cf][nf]

    PVSTAGE(0, 0);
    PVSTAGE(1, 64);
    for (int kt2 = 0; kt2 < 62; kt2 += 2) {
        PVBODY(0, kt2 + 0, true, "4");
        PVBODY(1, kt2 + 1, true, "4");
    }
    PVBODY(0, 62, false, "4");
    PVBODY(1, 63, false, "0");

    // epilogue: out = x_t + acc / den[n]
    const float* denb = den + (size_t)b * NTOK;
    float inv[2];
    #pragma unroll
    for (int nf = 0; nf < 2; ++nf) inv[nf] = 1.0f / denb[bn * 128 + wc * 32 + nf * 16 + lr];

    const float* xtp = x + (size_t)(b + NBATCH) * CIN * NTOK;
    float* op = out + (size_t)(b + NBATCH) * CIN * NTOK;
    #pragma unroll
    for (int cf = 0; cf < 4; ++cf) {
        #pragma unroll
        for (int nf = 0; nf < 2; ++nf) {
            #pragma unroll
            for (int r = 0; r < 4; ++r) {
                const int c = bm * 128 + wr * 64 + cf * 16 + lg * 4 + r;
                const int n = bn * 128 + wc * 32 + nf * 16 + lr;
                const size_t idx2 = (size_t)c * NTOK + n;
                op[idx2] = xtp[idx2] + acc[cf][nf][r] * inv[nf];
            }
        }
    }
}

extern "C" void kernel_launch(void* const* d_in, const int* in_sizes, int n_in,
                              void* d_out, int out_size, void* d_ws, size_t ws_size,
                              hipStream_t stream)
{
    (void)in_sizes; (void)n_in; (void)out_size; (void)ws_size;
    const float* x  = (const float*)d_in[0];
    const float* Wq = (const float*)d_in[1];
    const float* bq = (const float*)d_in[2];
    const float* Wk = (const float*)d_in[3];
    const float* bk = (const float*)d_in[4];
    const float* Wv = (const float*)d_in[5];
    const float* bv = (const float*)d_in[6];
    float* out = (float*)d_out;

    // ws layout (~148.1 MB): Qh 2MB | Kh 2MB | Vb 16MB | den 64KB | P 128MB
    // Wh (f16 weights, 640KB) aliases the head of P (dead before qk_exp writes P).
    u16* Qh = (u16*)d_ws;
    u16* Kh = Qh + (size_t)NBATCH * NTOK * OQK;
    u16* Vb = Kh + (size_t)NBATCH * NTOK * OQK;
    float* den = (float*)(Vb + (size_t)NBATCH * CIN * NTOK);
    u16* P  = (u16*)(den + (size_t)NBATCH * NTOK);
    u16* Wh = P;

    wcvt    <<<320, 256, 0, stream>>>(Wq, Wk, Wv, Wh);
    proj_all<<<dim3(128, NBATCH), 512, 0, stream>>>(x, bq, bk, bv, Wh, Qh, Kh, Vb, out);
    qk_exp  <<<1024, 256, 0, stream>>>(Qh, Kh, P, den);
    pv      <<<512, 512, 0, stream>>>(x, Vb, P, den, out);
}

// Round 20
// 187.334 us; speedup vs baseline: 1.1840x; 1.1262x over previous
//
#include <hip/hip_runtime.h>
#include <hip/hip_bf16.h>

#define CIN 512
#define OQK 64
#define NBATCH 4
#define NTOK 4096
#define L2E 1.44269504088896f

typedef float f32x4 __attribute__((ext_vector_type(4)));
typedef _Float16 f16x8 __attribute__((ext_vector_type(8)));
typedef short s16x8 __attribute__((ext_vector_type(8)));
typedef unsigned short u16;
typedef unsigned int u32;
typedef u32 u32x2 __attribute__((ext_vector_type(2)));
typedef u16 u16x4 __attribute__((ext_vector_type(4)));

__device__ inline u16 f2bf(float f) {
    unsigned u = __float_as_uint(f);
    u += 0x7fffu + ((u >> 16) & 1u);
    return (u16)(u >> 16);
}
__device__ inline u16 f2h_bits(float f) {
    _Float16 h = (_Float16)f;
    return __builtin_bit_cast(unsigned short, h);
}
// packed f32x2 -> bf16x2 (RTNE, same bits as f2bf) in ONE VALU op
__device__ inline u32 cvtpk_bf16(float lo, float hi) {
    u32 r;
    asm("v_cvt_pk_bf16_f32 %0, %1, %2" : "=v"(r) : "v"(lo), "v"(hi));
    return r;
}

#define GLOAD16(gp, lp) __builtin_amdgcn_global_load_lds(                        \
    (const __attribute__((address_space(1))) void*)(gp),                         \
    (__attribute__((address_space(3))) void*)(lp), 16, 0, 0)

// ---------------- W f32 -> f16 FRAGMENT-ORDER pre-convert ----------------
// NEW (r20): weights are emitted in MFMA fragment order so proj_all's wave
// loads are single contiguous 1KB segments:
//   Wf[g][t][l][j] = W[g*16 + (l&15)][t*32 + (l>>4)*8 + j]
// (g = 16-row output group, t = K-subtile, l = lane, j = 0..7)
// Layout: Wq frags [0, 32768), Wk [32768, 65536), Wv [65536, 327680).
__global__ __launch_bounds__(256) void wcvt(
    const float* __restrict__ Wq, const float* __restrict__ Wk,
    const float* __restrict__ Wv, u16* __restrict__ Wh)
{
    const int tid = blockIdx.x * 256 + threadIdx.x;   // 0..40959 lane-fragments
    if (tid >= 40960) return;
    const float* src; u16* dst; int fi;
    if (tid < 4096)       { src = Wq; dst = Wh;         fi = tid; }
    else if (tid < 8192)  { src = Wk; dst = Wh + 32768; fi = tid - 4096; }
    else                  { src = Wv; dst = Wh + 65536; fi = tid - 8192; }
    const int l = fi & 63, gt = fi >> 6;
    const int t = gt & 15, g = gt >> 4;
    const int row = g * 16 + (l & 15);
    const int col = t * 32 + (l >> 4) * 8;
    const float* p = src + (size_t)row * CIN + col;
    f32x4 a = *reinterpret_cast<const f32x4*>(p);
    f32x4 b = *reinterpret_cast<const f32x4*>(p + 4);
    u16x4 h0, h1;
    #pragma unroll
    for (int j = 0; j < 4; ++j) { h0[j] = f2h_bits(a[j]); h1[j] = f2h_bits(b[j]); }
    *reinterpret_cast<u16x4*>(dst + (size_t)fi * 8)     = h0;
    *reinterpret_cast<u16x4*>(dst + (size_t)fi * 8 + 4) = h1;
}

// ---------------- fused Q/K/V projections + x_s passthrough ----------------
// r16-verified structure; NEW (r20): weight fragment loads are contiguous
// (base + l*8) -- one coalesced 1KB segment per wave per fragment.
__global__ __launch_bounds__(512, 4) void proj_all(
    const float* __restrict__ x,
    const float* __restrict__ bq, const float* __restrict__ bk, const float* __restrict__ bv,
    const u16* __restrict__ Wh,
    u16* __restrict__ Qh, u16* __restrict__ Kh, u16* __restrict__ Vb,
    float* __restrict__ out)
{
    __shared__ u16 Ls[32 * 520];
    __shared__ u16 Lt[32 * 520];

    const int nb = blockIdx.x;   // 128 panels of 32 tokens
    const int b  = blockIdx.y;   // 4
    const int tid = threadIdx.x;
    const int w = tid >> 6, l = tid & 63;
    const int lr = l & 15, lg = l >> 4;
    const int n0 = nb * 32;

    const float* xs = x + (size_t)b * CIN * NTOK;
    const float* xt = x + (size_t)(b + NBATCH) * CIN * NTOK;
    float* os = out + (size_t)b * CIN * NTOK;

    // ---- stage both panels (threads 0-255: x_s + out copy; 256-511: x_t) ----
    {
        const int sg = tid >> 8, st = tid & 255;
        const int q = st & 7, cpb = st >> 3;     // n-quad, channel-pair base
        const float* src = sg ? xt : xs;
        u16* Lp = sg ? Lt : Ls;
        #pragma unroll
        for (int r = 0; r < 8; ++r) {
            const int c0 = (cpb + r * 32) * 2;
            f32x4 va = *reinterpret_cast<const f32x4*>(src + (size_t)c0 * NTOK + n0 + q * 4);
            f32x4 vb = *reinterpret_cast<const f32x4*>(src + (size_t)(c0 + 1) * NTOK + n0 + q * 4);
            if (!sg) {
                *reinterpret_cast<f32x4*>(os + (size_t)c0 * NTOK + n0 + q * 4) = va;
                *reinterpret_cast<f32x4*>(os + (size_t)(c0 + 1) * NTOK + n0 + q * 4) = vb;
            }
            #pragma unroll
            for (int j = 0; j < 4; ++j) {
                u32 pk = (u32)f2h_bits(va[j]) | ((u32)f2h_bits(vb[j]) << 16);
                *reinterpret_cast<u32*>(&Lp[(q * 4 + j) * 520 + c0]) = pk;
            }
        }
    }
    __syncthreads();

    const u16* Wqf = Wh;
    const u16* Wkf = Wh + 32768;
    const u16* Wvf = Wh + 65536;
    const bool isq = (w < 4);
    const int h  = isq ? (w >> 1) : 0;            // Q: token-half
    const int ob = isq ? ((w & 1) * 2) : (w - 4); // Q: o-pair base; K: o-quarter

    f32x4 macc[4][2] = {};   // V accum [cf][fm]  (D[m][c] orientation)
    f32x4 xacc[2] = {};      // Q (i) or K (h2)   (D[o][n] orientation)

    #pragma unroll 4
    for (int t = 0; t < 16; ++t) {
        const int c0 = t * 32 + lg * 8;
        f16x8 X0 = *reinterpret_cast<const f16x8*>(&Lt[lr * 520 + c0]);
        f16x8 X1 = *reinterpret_cast<const f16x8*>(&Lt[(16 + lr) * 520 + c0]);
        #pragma unroll
        for (int cf = 0; cf < 4; ++cf) {
            // group g = w*4 + cf; fragment base = ((g*16 + t)*64 + l)*8
            f16x8 Wvv = *reinterpret_cast<const f16x8*>(&Wvf[(size_t)(((w * 4 + cf) * 16 + t) * 64 + l) * 8]);
            macc[cf][0] = __builtin_amdgcn_mfma_f32_16x16x32_f16(X0, Wvv, macc[cf][0], 0, 0, 0);
            macc[cf][1] = __builtin_amdgcn_mfma_f32_16x16x32_f16(X1, Wvv, macc[cf][1], 0, 0, 0);
        }
        if (isq) {
            f16x8 Xs = *reinterpret_cast<const f16x8*>(&Ls[(h * 16 + lr) * 520 + c0]);
            #pragma unroll
            for (int i = 0; i < 2; ++i) {
                f16x8 Wqv = *reinterpret_cast<const f16x8*>(&Wqf[(size_t)((((ob + i) * 16) + t) * 64 + l) * 8]);
                xacc[i] = __builtin_amdgcn_mfma_f32_16x16x32_f16(Wqv, Xs, xacc[i], 0, 0, 0);
            }
        } else {
            f16x8 Wkv = *reinterpret_cast<const f16x8*>(&Wkf[(size_t)((ob * 16 + t) * 64 + l) * 8]);
            xacc[0] = __builtin_amdgcn_mfma_f32_16x16x32_f16(Wkv, X0, xacc[0], 0, 0, 0);
            xacc[1] = __builtin_amdgcn_mfma_f32_16x16x32_f16(Wkv, X1, xacc[1], 0, 0, 0);
        }
    }

    // ---- V store: packed bf16x4 along m (cvt_pk) ----
    #pragma unroll
    for (int cf = 0; cf < 4; ++cf) {
        const int c = w * 64 + cf * 16 + lr;
        const float bvc = bv[c];
        #pragma unroll
        for (int fm = 0; fm < 2; ++fm) {
            u32x2 pk;
            pk[0] = cvtpk_bf16(macc[cf][fm][0] + bvc, macc[cf][fm][1] + bvc);
            pk[1] = cvtpk_bf16(macc[cf][fm][2] + bvc, macc[cf][fm][3] + bvc);
            *reinterpret_cast<u32x2*>(&Vb[((size_t)b * CIN + c) * NTOK + n0 + fm * 16 + lg * 4]) = pk;
        }
    }
    // ---- Q / K store: packed f16x4 along o.  Q scaled by log2(e). ----
    if (isq) {
        #pragma unroll
        for (int i = 0; i < 2; ++i) {
            u16x4 pk;
            #pragma unroll
            for (int r = 0; r < 4; ++r)
                pk[r] = f2h_bits((xacc[i][r] + bq[(ob + i) * 16 + lg * 4 + r]) * L2E);
            *reinterpret_cast<u16x4*>(&Qh[((size_t)b * NTOK + n0 + h * 16 + lr) * OQK + (ob + i) * 16 + lg * 4]) = pk;
        }
    } else {
        #pragma unroll
        for (int h2 = 0; h2 < 2; ++h2) {
            u16x4 pk;
            #pragma unroll
            for (int r = 0; r < 4; ++r) pk[r] = f2h_bits(xacc[h2][r] + bk[ob * 16 + lg * 4 + r]);
            *reinterpret_cast<u16x4*>(&Kh[((size_t)b * NTOK + n0 + h2 * 16 + lr) * OQK + ob * 16 + lg * 4]) = pk;
        }
    }
}

// ---------------- pass S: P = exp2(K Q'^T) (bf16) + exact den (r16-verified) ----------------

#define SLOADK(mt, KF)                                                          \
  { _Pragma("unroll")                                                           \
    for (int mf_ = 0; mf_ < 4; ++mf_) {                                         \
      const u16* kp = Kbase + (size_t)((mt) * 64 + mf_ * 16 + lr) * OQK + lg * 8; \
      KF[mf_][0] = *reinterpret_cast<const f16x8*>(kp);                         \
      KF[mf_][1] = *reinterpret_cast<const f16x8*>(kp + 32);                    \
    } }

#define STILE(mt, KF)                                                           \
  { _Pragma("unroll")                                                           \
    for (int mf_ = 0; mf_ < 4; ++mf_) {                                         \
      f32x4 s_ = {};                                                            \
      s_ = __builtin_amdgcn_mfma_f32_16x16x32_f16(KF[mf_][0], Bq0, s_, 0, 0, 0);\
      s_ = __builtin_amdgcn_mfma_f32_16x16x32_f16(KF[mf_][1], Bq1, s_, 0, 0, 0);\
      float p0 = exp2f(s_[0]), p1 = exp2f(s_[1]);                               \
      float p2 = exp2f(s_[2]), p3 = exp2f(s_[3]);                               \
      denl += (p0 + p1) + (p2 + p3);                                            \
      u32x2 pk;                                                                 \
      pk[0] = cvtpk_bf16(p0, p1);                                               \
      pk[1] = cvtpk_bf16(p2, p3);                                               \
      const int widx_ = (lr * 64 + mf_ * 16 + lg * 4) ^ ((lr & 7) << 3);        \
      *reinterpret_cast<u32x2*>(&Tw[widx_]) = pk;                               \
    }                                                                           \
    _Pragma("unroll")                                                           \
    for (int rr_ = 0; rr_ < 2; ++rr_) {                                         \
      const int nl_ = (l >> 3) + rr_ * 8;                                       \
      const int ridx_ = (nl_ * 64 + (l & 7) * 8) ^ ((nl_ & 7) << 3);            \
      s16x8 v_ = *reinterpret_cast<const s16x8*>(&Tw[ridx_]);                   \
      *reinterpret_cast<s16x8*>(&Pp[(size_t)(grp * 16 + nl_) * NTOK + (mt) * 64 + (l & 7) * 8]) = v_; \
    } }

__global__ __launch_bounds__(256, 4) void qk_exp(
    const u16* __restrict__ Qh, const u16* __restrict__ Kh,
    u16* __restrict__ P, float* __restrict__ den)
{
    __shared__ float dpart[4][16];
    __shared__ u16 T[4][1024];                     // per-wave 16x64 transpose tile
    const int g = blockIdx.x;
    const int xcd = g & 7;
    const int b = xcd >> 1;
    const int grp = ((g >> 3) << 1) | (xcd & 1);   // 16-row group (0..255)

    const int tid = threadIdx.x;
    const int w = tid >> 6, l = tid & 63;
    const int lr = l & 15, lg = l >> 4;

    const int n = grp * 16 + lr;
    const int mbase = w * 1024;                    // wave's m-quarter
    const u16* Kbase = Kh + ((size_t)b * NTOK + mbase) * OQK;
    u16* Pp = P + (size_t)b * NTOK * NTOK + mbase;
    u16* Tw = T[w];

    f16x8 Bq0, Bq1;
    {
        const u16* qp = Qh + ((size_t)b * NTOK + n) * OQK + lg * 8;
        Bq0 = *reinterpret_cast<const f16x8*>(qp);
        Bq1 = *reinterpret_cast<const f16x8*>(qp + 32);
    }

    float denl = 0.f;
    f16x8 KfA[4][2], KfB[4][2];

    SLOADK(0, KfA);
    for (int mt = 0; mt < 16; mt += 2) {
        SLOADK(mt + 1, KfB);
        STILE(mt, KfA);
        if (mt + 2 < 16) SLOADK(mt + 2, KfA);
        STILE(mt + 1, KfB);
    }

    denl += __shfl_xor(denl, 16);
    denl += __shfl_xor(denl, 32);
    if (l < 16) dpart[w][l] = denl;
    __syncthreads();
    if (tid < 16)
        den[(size_t)b * NTOK + grp * 16 + tid] =
            (dpart[0][tid] + dpart[1][tid]) + (dpart[2][tid] + dpart[3][tid]);
}

// ---------------- pass PV: out = x_t + (V P^T) / den (r19-verified, ~79 us) ----------------
// BK=64, 64 K-tiles, 512 thr (8 waves, wave = 64c x 32n, 16 MFMA + 12 ds_read
// per tile). 2 bufs x 32KB = 64KB LDS -> 2 blocks/CU = 16 waves/CU.
// Stage(kt+2) after 2nd barrier; steady vmcnt(4), tail 4/0.
// Swizzle: slot ^= row&7 (involution). XCD P-sharing map (r14).

#define PVSTAGE(BUF, m0)                                                        \
  { _Pragma("unroll")                                                           \
    for (int i_ = 0; i_ < 2; ++i_) {                                            \
      const int chunk_ = i_ * 512 + tid;                                        \
      const int row_ = chunk_ >> 3;                                             \
      const int sl_ = (chunk_ & 7) ^ (row_ & 7);                                \
      GLOAD16(Abase + (size_t)row_ * NTOK + (m0) + sl_ * 8,                     \
              &AS[(BUF) * 8192 + chunk_ * 8]);                                  \
    }                                                                           \
    _Pragma("unroll")                                                           \
    for (int j_ = 0; j_ < 2; ++j_) {                                            \
      const int chunk_ = j_ * 512 + tid;                                        \
      const int row_ = chunk_ >> 3;                                             \
      const int sl_ = (chunk_ & 7) ^ (row_ & 7);                                \
      GLOAD16(Bbase + (size_t)row_ * NTOK + (m0) + sl_ * 8,                     \
              &BS[(BUF) * 8192 + chunk_ * 8]);                                  \
    } }

#define PVBODY(CUR, kt, DOSTAGE, VM)                                            \
  {                                                                             \
    asm volatile("s_waitcnt vmcnt(" VM ")" ::: "memory");                       \
    __builtin_amdgcn_s_barrier();                                               \
    s16x8 Af[4][2], Bf[2][2];                                                   \
    _Pragma("unroll")                                                           \
    for (int cf_ = 0; cf_ < 4; ++cf_) {                                         \
      const int r_ = wr * 64 + cf_ * 16 + lr;                                   \
      _Pragma("unroll")                                                         \
      for (int kk_ = 0; kk_ < 2; ++kk_) {                                       \
        const int s_ = (kk_ * 4 + lg) ^ (r_ & 7);                               \
        Af[cf_][kk_] = *(const s16x8*)&AS[(CUR) * 8192 + r_ * 64 + s_ * 8];     \
      } }                                                                       \
    _Pragma("unroll")                                                           \
    for (int nf_ = 0; nf_ < 2; ++nf_) {                                         \
      const int r_ = wc * 32 + nf_ * 16 + lr;                                   \
      _Pragma("unroll")                                                         \
      for (int kk_ = 0; kk_ < 2; ++kk_) {                                       \
        const int s_ = (kk_ * 4 + lg) ^ (r_ & 7);                               \
        Bf[nf_][kk_] = *(const s16x8*)&BS[(CUR) * 8192 + r_ * 64 + s_ * 8];     \
      } }                                                                       \
    __builtin_amdgcn_s_setprio(1);                                              \
    _Pragma("unroll")                                                           \
    for (int cf_ = 0; cf_ < 4; ++cf_)                                           \
      _Pragma("unroll")                                                         \
      for (int nf_ = 0; nf_ < 2; ++nf_)                                         \
        acc[cf_][nf_] = __builtin_amdgcn_mfma_f32_16x16x32_bf16(Af[cf_][0], Bf[nf_][0], acc[cf_][nf_], 0, 0, 0); \
    _Pragma("unroll")                                                           \
    for (int cf_ = 0; cf_ < 4; ++cf_)                                           \
      _Pragma("unroll")                                                         \
      for (int nf_ = 0; nf_ < 2; ++nf_)                                         \
        acc[cf_][nf_] = __builtin_amdgcn_mfma_f32_16x16x32_bf16(Af[cf_][1], Bf[nf_][1], acc[cf_][nf_], 0, 0, 0); \
    __builtin_amdgcn_s_setprio(0);                                              \
    __builtin_amdgcn_s_barrier();                                               \
    if (DOSTAGE) PVSTAGE(CUR, ((kt) + 2) * 64);                                 \
  }

__global__ __launch_bounds__(512, 2) void pv(
    const float* __restrict__ x, const u16* __restrict__ Vb,
    const u16* __restrict__ P, const float* __restrict__ den,
    float* __restrict__ out)
{
    __shared__ u16 AS[2 * 8192];   // 2 bufs x 128rows x 64k  (V)  32 KB
    __shared__ u16 BS[2 * 8192];   // 2 bufs x 128rows x 64k  (P)  32 KB

    const int g = blockIdx.x;
    const int xcd = g & 7;
    const int b = xcd >> 1;
    const int idx = ((g >> 3) << 1) | (xcd & 1);  // 0..127 per batch
    const int bm = (idx >> 1) & 3;                // c-tile: sharers same XCD
    const int bn = ((idx >> 3) << 1) | (idx & 1); // n-tile 0..31

    const int tid = threadIdx.x;
    const int w = tid >> 6, l = tid & 63;
    const int lr = l & 15, lg = l >> 4;
    const int wr = w >> 2, wc = w & 3;            // wave: 64c x 32n

    const u16* Abase = Vb + (size_t)b * CIN * NTOK + (size_t)(bm * 128) * NTOK;
    const u16* Bbase = P + (size_t)b * NTOK * NTOK + (size_t)(bn * 128) * NTOK;

    f32x4 acc[4][2] = {};                         // [cf][nf]

    PVSTAGE(0, 0);
    PVSTAGE(1, 64);
    for (int kt2 = 0; kt2 < 62; kt2 += 2) {
        PVBODY(0, kt2 + 0, true, "4");
        PVBODY(1, kt2 + 1, true, "4");
    }
    PVBODY(0, 62, false, "4");
    PVBODY(1, 63, false, "0");

    // epilogue: out = x_t + acc / den[n]
    const float* denb = den + (size_t)b * NTOK;
    float inv[2];
    #pragma unroll
    for (int nf = 0; nf < 2; ++nf) inv[nf] = 1.0f / denb[bn * 128 + wc * 32 + nf * 16 + lr];

    const float* xtp = x + (size_t)(b + NBATCH) * CIN * NTOK;
    float* op = out + (size_t)(b + NBATCH) * CIN * NTOK;
    #pragma unroll
    for (int cf = 0; cf < 4; ++cf) {
        #pragma unroll
        for (int nf = 0; nf < 2; ++nf) {
            #pragma unroll
            for (int r = 0; r < 4; ++r) {
                const int c = bm * 128 + wr * 64 + cf * 16 + lg * 4 + r;
                const int n = bn * 128 + wc * 32 + nf * 16 + lr;
                const size_t idx2 = (size_t)c * NTOK + n;
                op[idx2] = xtp[idx2] + acc[cf][nf][r] * inv[nf];
            }
        }
    }
}

extern "C" void kernel_launch(void* const* d_in, const int* in_sizes, int n_in,
                              void* d_out, int out_size, void* d_ws, size_t ws_size,
                              hipStream_t stream)
{
    (void)in_sizes; (void)n_in; (void)out_size; (void)ws_size;
    const float* x  = (const float*)d_in[0];
    const float* Wq = (const float*)d_in[1];
    const float* bq = (const float*)d_in[2];
    const float* Wk = (const float*)d_in[3];
    const float* bk = (const float*)d_in[4];
    const float* Wv = (const float*)d_in[5];
    const float* bv = (const float*)d_in[6];
    float* out = (float*)d_out;

    // ws layout (~148.1 MB): Qh 2MB | Kh 2MB | Vb 16MB | den 64KB | P 128MB
    // Wh (fragment-ordered f16 weights, 640KB) aliases the head of P (dead
    // before qk_exp writes P).
    u16* Qh = (u16*)d_ws;
    u16* Kh = Qh + (size_t)NBATCH * NTOK * OQK;
    u16* Vb = Kh + (size_t)NBATCH * NTOK * OQK;
    float* den = (float*)(Vb + (size_t)NBATCH * CIN * NTOK);
    u16* P  = (u16*)(den + (size_t)NBATCH * NTOK);
    u16* Wh = P;

    wcvt    <<<160, 256, 0, stream>>>(Wq, Wk, Wv, Wh);
    proj_all<<<dim3(128, NBATCH), 512, 0, stream>>>(x, bq, bk, bv, Wh, Qh, Kh, Vb, out);
    qk_exp  <<<1024, 256, 0, stream>>>(Qh, Kh, P, den);
    pv      <<<512, 512, 0, stream>>>(x, Vb, P, den, out);
}

// Round 21
// 157.743 us; speedup vs baseline: 1.4061x; 1.1876x over previous
//
#include <hip/hip_runtime.h>
#include <hip/hip_bf16.h>

#define CIN 512
#define OQK 64
#define NBATCH 4
#define NTOK 4096
#define L2E 1.44269504088896f

typedef float f32x4 __attribute__((ext_vector_type(4)));
typedef _Float16 f16x8 __attribute__((ext_vector_type(8)));
typedef short s16x8 __attribute__((ext_vector_type(8)));
typedef unsigned short u16;
typedef unsigned int u32;
typedef u32 u32x2 __attribute__((ext_vector_type(2)));
typedef u16 u16x4 __attribute__((ext_vector_type(4)));

__device__ inline u16 f2bf(float f) {
    unsigned u = __float_as_uint(f);
    u += 0x7fffu + ((u >> 16) & 1u);
    return (u16)(u >> 16);
}
__device__ inline u16 f2h_bits(float f) {
    _Float16 h = (_Float16)f;
    return __builtin_bit_cast(unsigned short, h);
}
// packed f32x2 -> bf16x2 (RTNE, same bits as f2bf) in ONE VALU op
__device__ inline u32 cvtpk_bf16(float lo, float hi) {
    u32 r;
    asm("v_cvt_pk_bf16_f32 %0, %1, %2" : "=v"(r) : "v"(lo), "v"(hi));
    return r;
}

#define GLOAD16(gp, lp) __builtin_amdgcn_global_load_lds(                        \
    (const __attribute__((address_space(1))) void*)(gp),                         \
    (__attribute__((address_space(3))) void*)(lp), 16, 0, 0)

// ---------------- W f32 -> f16 FRAGMENT-ORDER pre-convert (r20-verified) ----------------
// Wf[g][t][l][j] = W[g*16 + (l&15)][t*32 + (l>>4)*8 + j]
__global__ __launch_bounds__(256) void wcvt(
    const float* __restrict__ Wq, const float* __restrict__ Wk,
    const float* __restrict__ Wv, u16* __restrict__ Wh)
{
    const int tid = blockIdx.x * 256 + threadIdx.x;   // 0..40959 lane-fragments
    if (tid >= 40960) return;
    const float* src; u16* dst; int fi;
    if (tid < 4096)       { src = Wq; dst = Wh;         fi = tid; }
    else if (tid < 8192)  { src = Wk; dst = Wh + 32768; fi = tid - 4096; }
    else                  { src = Wv; dst = Wh + 65536; fi = tid - 8192; }
    const int l = fi & 63, gt = fi >> 6;
    const int t = gt & 15, g = gt >> 4;
    const int row = g * 16 + (l & 15);
    const int col = t * 32 + (l >> 4) * 8;
    const float* p = src + (size_t)row * CIN + col;
    f32x4 a = *reinterpret_cast<const f32x4*>(p);
    f32x4 b = *reinterpret_cast<const f32x4*>(p + 4);
    u16x4 h0, h1;
    #pragma unroll
    for (int j = 0; j < 4; ++j) { h0[j] = f2h_bits(a[j]); h1[j] = f2h_bits(b[j]); }
    *reinterpret_cast<u16x4*>(dst + (size_t)fi * 8)     = h0;
    *reinterpret_cast<u16x4*>(dst + (size_t)fi * 8 + 4) = h1;
}

// ---------------- fused Q/K/V projections + x_s passthrough ----------------
// r20-verified structure. NEW (r21): K is stored in MFMA FRAGMENT ORDER
//   Kf[b][mg][half][l][j] = K[b][mg*16 + (l&15)][half*32 + (l>>4)*8 + j]
// so qk_exp's K loads become contiguous 1KB wave segments. Writer mapping
// (bijective, 512B-coalesced): lane' = lr + ((ob&1)*2 + (lg>>1))*16,
// j = (lg&1)*4 + r, mg = nb*2 + h2, half = ob>>1.
__global__ __launch_bounds__(512, 4) void proj_all(
    const float* __restrict__ x,
    const float* __restrict__ bq, const float* __restrict__ bk, const float* __restrict__ bv,
    const u16* __restrict__ Wh,
    u16* __restrict__ Qh, u16* __restrict__ Kf, u16* __restrict__ Vb,
    float* __restrict__ out)
{
    __shared__ u16 Ls[32 * 520];
    __shared__ u16 Lt[32 * 520];

    const int nb = blockIdx.x;   // 128 panels of 32 tokens
    const int b  = blockIdx.y;   // 4
    const int tid = threadIdx.x;
    const int w = tid >> 6, l = tid & 63;
    const int lr = l & 15, lg = l >> 4;
    const int n0 = nb * 32;

    const float* xs = x + (size_t)b * CIN * NTOK;
    const float* xt = x + (size_t)(b + NBATCH) * CIN * NTOK;
    float* os = out + (size_t)b * CIN * NTOK;

    // ---- stage both panels (threads 0-255: x_s + out copy; 256-511: x_t) ----
    {
        const int sg = tid >> 8, st = tid & 255;
        const int q = st & 7, cpb = st >> 3;     // n-quad, channel-pair base
        const float* src = sg ? xt : xs;
        u16* Lp = sg ? Lt : Ls;
        #pragma unroll
        for (int r = 0; r < 8; ++r) {
            const int c0 = (cpb + r * 32) * 2;
            f32x4 va = *reinterpret_cast<const f32x4*>(src + (size_t)c0 * NTOK + n0 + q * 4);
            f32x4 vb = *reinterpret_cast<const f32x4*>(src + (size_t)(c0 + 1) * NTOK + n0 + q * 4);
            if (!sg) {
                *reinterpret_cast<f32x4*>(os + (size_t)c0 * NTOK + n0 + q * 4) = va;
                *reinterpret_cast<f32x4*>(os + (size_t)(c0 + 1) * NTOK + n0 + q * 4) = vb;
            }
            #pragma unroll
            for (int j = 0; j < 4; ++j) {
                u32 pk = (u32)f2h_bits(va[j]) | ((u32)f2h_bits(vb[j]) << 16);
                *reinterpret_cast<u32*>(&Lp[(q * 4 + j) * 520 + c0]) = pk;
            }
        }
    }
    __syncthreads();

    const u16* Wqf = Wh;
    const u16* Wkf = Wh + 32768;
    const u16* Wvf = Wh + 65536;
    const bool isq = (w < 4);
    const int h  = isq ? (w >> 1) : 0;            // Q: token-half
    const int ob = isq ? ((w & 1) * 2) : (w - 4); // Q: o-pair base; K: o-quarter

    f32x4 macc[4][2] = {};   // V accum [cf][fm]  (D[m][c] orientation)
    f32x4 xacc[2] = {};      // Q (i) or K (h2)   (D[o][n] orientation)

    #pragma unroll 4
    for (int t = 0; t < 16; ++t) {
        const int c0 = t * 32 + lg * 8;
        f16x8 X0 = *reinterpret_cast<const f16x8*>(&Lt[lr * 520 + c0]);
        f16x8 X1 = *reinterpret_cast<const f16x8*>(&Lt[(16 + lr) * 520 + c0]);
        #pragma unroll
        for (int cf = 0; cf < 4; ++cf) {
            f16x8 Wvv = *reinterpret_cast<const f16x8*>(&Wvf[(size_t)(((w * 4 + cf) * 16 + t) * 64 + l) * 8]);
            macc[cf][0] = __builtin_amdgcn_mfma_f32_16x16x32_f16(X0, Wvv, macc[cf][0], 0, 0, 0);
            macc[cf][1] = __builtin_amdgcn_mfma_f32_16x16x32_f16(X1, Wvv, macc[cf][1], 0, 0, 0);
        }
        if (isq) {
            f16x8 Xs = *reinterpret_cast<const f16x8*>(&Ls[(h * 16 + lr) * 520 + c0]);
            #pragma unroll
            for (int i = 0; i < 2; ++i) {
                f16x8 Wqv = *reinterpret_cast<const f16x8*>(&Wqf[(size_t)((((ob + i) * 16) + t) * 64 + l) * 8]);
                xacc[i] = __builtin_amdgcn_mfma_f32_16x16x32_f16(Wqv, Xs, xacc[i], 0, 0, 0);
            }
        } else {
            f16x8 Wkv = *reinterpret_cast<const f16x8*>(&Wkf[(size_t)((ob * 16 + t) * 64 + l) * 8]);
            xacc[0] = __builtin_amdgcn_mfma_f32_16x16x32_f16(Wkv, X0, xacc[0], 0, 0, 0);
            xacc[1] = __builtin_amdgcn_mfma_f32_16x16x32_f16(Wkv, X1, xacc[1], 0, 0, 0);
        }
    }

    // ---- V store: packed bf16x4 along m (cvt_pk) ----
    #pragma unroll
    for (int cf = 0; cf < 4; ++cf) {
        const int c = w * 64 + cf * 16 + lr;
        const float bvc = bv[c];
        #pragma unroll
        for (int fm = 0; fm < 2; ++fm) {
            u32x2 pk;
            pk[0] = cvtpk_bf16(macc[cf][fm][0] + bvc, macc[cf][fm][1] + bvc);
            pk[1] = cvtpk_bf16(macc[cf][fm][2] + bvc, macc[cf][fm][3] + bvc);
            *reinterpret_cast<u32x2*>(&Vb[((size_t)b * CIN + c) * NTOK + n0 + fm * 16 + lg * 4]) = pk;
        }
    }
    // ---- Q store: packed f16x4 along o (row-major), Q scaled by log2(e) ----
    if (isq) {
        #pragma unroll
        for (int i = 0; i < 2; ++i) {
            u16x4 pk;
            #pragma unroll
            for (int r = 0; r < 4; ++r)
                pk[r] = f2h_bits((xacc[i][r] + bq[(ob + i) * 16 + lg * 4 + r]) * L2E);
            *reinterpret_cast<u16x4*>(&Qh[((size_t)b * NTOK + n0 + h * 16 + lr) * OQK + (ob + i) * 16 + lg * 4]) = pk;
        }
    } else {
        // ---- K store: FRAGMENT ORDER (r21) ----
        const int lanep = lr + ((ob & 1) * 2 + (lg >> 1)) * 16;
        #pragma unroll
        for (int h2 = 0; h2 < 2; ++h2) {
            u16x4 pk;
            #pragma unroll
            for (int r = 0; r < 4; ++r) pk[r] = f2h_bits(xacc[h2][r] + bk[ob * 16 + lg * 4 + r]);
            u16* dst = Kf + (((size_t)b * 256 + nb * 2 + h2) * 2 + (ob >> 1)) * 512
                          + lanep * 8 + (lg & 1) * 4;
            *reinterpret_cast<u16x4*>(dst) = pk;
        }
    }
}

// ---------------- pass S: P = exp2(K Q'^T) (bf16) + exact den ----------------
// r16-verified core; NEW (r21): K loads from fragment-ordered Kf --
// one contiguous 1KB wave segment per (mt, mf, half).

#define SLOADK(mt, KF)                                                          \
  { _Pragma("unroll")                                                           \
    for (int mf_ = 0; mf_ < 4; ++mf_) {                                         \
      _Pragma("unroll")                                                         \
      for (int kk_ = 0; kk_ < 2; ++kk_)                                         \
        KF[mf_][kk_] = *reinterpret_cast<const f16x8*>(                         \
            &Kfrag[(((size_t)(w * 64 + (mt) * 4 + mf_)) * 2 + kk_) * 512 + l * 8]); \
    } }

#define STILE(mt, KF)                                                           \
  { _Pragma("unroll")                                                           \
    for (int mf_ = 0; mf_ < 4; ++mf_) {                                         \
      f32x4 s_ = {};                                                            \
      s_ = __builtin_amdgcn_mfma_f32_16x16x32_f16(KF[mf_][0], Bq0, s_, 0, 0, 0);\
      s_ = __builtin_amdgcn_mfma_f32_16x16x32_f16(KF[mf_][1], Bq1, s_, 0, 0, 0);\
      float p0 = exp2f(s_[0]), p1 = exp2f(s_[1]);                               \
      float p2 = exp2f(s_[2]), p3 = exp2f(s_[3]);                               \
      denl += (p0 + p1) + (p2 + p3);                                            \
      u32x2 pk;                                                                 \
      pk[0] = cvtpk_bf16(p0, p1);                                               \
      pk[1] = cvtpk_bf16(p2, p3);                                               \
      const int widx_ = (lr * 64 + mf_ * 16 + lg * 4) ^ ((lr & 7) << 3);        \
      *reinterpret_cast<u32x2*>(&Tw[widx_]) = pk;                               \
    }                                                                           \
    _Pragma("unroll")                                                           \
    for (int rr_ = 0; rr_ < 2; ++rr_) {                                         \
      const int nl_ = (l >> 3) + rr_ * 8;                                       \
      const int ridx_ = (nl_ * 64 + (l & 7) * 8) ^ ((nl_ & 7) << 3);            \
      s16x8 v_ = *reinterpret_cast<const s16x8*>(&Tw[ridx_]);                   \
      *reinterpret_cast<s16x8*>(&Pp[(size_t)(grp * 16 + nl_) * NTOK + (mt) * 64 + (l & 7) * 8]) = v_; \
    } }

__global__ __launch_bounds__(256, 4) void qk_exp(
    const u16* __restrict__ Qh, const u16* __restrict__ Kf,
    u16* __restrict__ P, float* __restrict__ den)
{
    __shared__ float dpart[4][16];
    __shared__ u16 T[4][1024];                     // per-wave 16x64 transpose tile
    const int g = blockIdx.x;
    const int xcd = g & 7;
    const int b = xcd >> 1;
    const int grp = ((g >> 3) << 1) | (xcd & 1);   // 16-row group (0..255)

    const int tid = threadIdx.x;
    const int w = tid >> 6, l = tid & 63;
    const int lr = l & 15, lg = l >> 4;

    const int n = grp * 16 + lr;
    const int mbase = w * 1024;                    // wave's m-quarter
    const u16* Kfrag = Kf + (size_t)b * 256 * 2 * 512;
    u16* Pp = P + (size_t)b * NTOK * NTOK + mbase;
    u16* Tw = T[w];

    f16x8 Bq0, Bq1;
    {
        const u16* qp = Qh + ((size_t)b * NTOK + n) * OQK + lg * 8;
        Bq0 = *reinterpret_cast<const f16x8*>(qp);
        Bq1 = *reinterpret_cast<const f16x8*>(qp + 32);
    }

    float denl = 0.f;
    f16x8 KfA[4][2], KfB[4][2];

    SLOADK(0, KfA);
    for (int mt = 0; mt < 16; mt += 2) {
        SLOADK(mt + 1, KfB);
        STILE(mt, KfA);
        if (mt + 2 < 16) SLOADK(mt + 2, KfA);
        STILE(mt + 1, KfB);
    }

    denl += __shfl_xor(denl, 16);
    denl += __shfl_xor(denl, 32);
    if (l < 16) dpart[w][l] = denl;
    __syncthreads();
    if (tid < 16)
        den[(size_t)b * NTOK + grp * 16 + tid] =
            (dpart[0][tid] + dpart[1][tid]) + (dpart[2][tid] + dpart[3][tid]);
}

// ---------------- pass PV: out = x_t + (V P^T) / den (r19-verified, ~78 us) ----------------
// BK=64, 64 K-tiles, 512 thr (8 waves, wave = 64c x 32n). 2 bufs x 32KB = 64KB
// LDS -> 2 blocks/CU = 16 waves/CU. Stage(kt+2) after 2nd barrier; steady
// vmcnt(4), tail 4/0. Swizzle: slot ^= row&7. XCD P-sharing map (r14).

#define PVSTAGE(BUF, m0)                                                        \
  { _Pragma("unroll")                                                           \
    for (int i_ = 0; i_ < 2; ++i_) {                                            \
      const int chunk_ = i_ * 512 + tid;                                        \
      const int row_ = chunk_ >> 3;                                             \
      const int sl_ = (chunk_ & 7) ^ (row_ & 7);                                \
      GLOAD16(Abase + (size_t)row_ * NTOK + (m0) + sl_ * 8,                     \
              &AS[(BUF) * 8192 + chunk_ * 8]);                                  \
    }                                                                           \
    _Pragma("unroll")                                                           \
    for (int j_ = 0; j_ < 2; ++j_) {                                            \
      const int chunk_ = j_ * 512 + tid;                                        \
      const int row_ = chunk_ >> 3;                                             \
      const int sl_ = (chunk_ & 7) ^ (row_ & 7);                                \
      GLOAD16(Bbase + (size_t)row_ * NTOK + (m0) + sl_ * 8,                     \
              &BS[(BUF) * 8192 + chunk_ * 8]);                                  \
    } }

#define PVBODY(CUR, kt, DOSTAGE, VM)                                            \
  {                                                                             \
    asm volatile("s_waitcnt vmcnt(" VM ")" ::: "memory");                       \
    __builtin_amdgcn_s_barrier();                                               \
    s16x8 Af[4][2], Bf[2][2];                                                   \
    _Pragma("unroll")                                                           \
    for (int cf_ = 0; cf_ < 4; ++cf_) {                                         \
      const int r_ = wr * 64 + cf_ * 16 + lr;                                   \
      _Pragma("unroll")                                                         \
      for (int kk_ = 0; kk_ < 2; ++kk_) {                                       \
        const int s_ = (kk_ * 4 + lg) ^ (r_ & 7);                               \
        Af[cf_][kk_] = *(const s16x8*)&AS[(CUR) * 8192 + r_ * 64 + s_ * 8];     \
      } }                                                                       \
    _Pragma("unroll")                                                           \
    for (int nf_ = 0; nf_ < 2; ++nf_) {                                         \
      const int r_ = wc * 32 + nf_ * 16 + lr;                                   \
      _Pragma("unroll")                                                         \
      for (int kk_ = 0; kk_ < 2; ++kk_) {                                       \
        const int s_ = (kk_ * 4 + lg) ^ (r_ & 7);                               \
        Bf[nf_][kk_] = *(const s16x8*)&BS[(CUR) * 8192 + r_ * 64 + s_ * 8];     \
      } }                                                                       \
    __builtin_amdgcn_s_setprio(1);                                              \
    _Pragma("unroll")                                                           \
    for (int cf_ = 0; cf_ < 4; ++cf_)                                           \
      _Pragma("unroll")                                                         \
      for (int nf_ = 0; nf_ < 2; ++nf_)                                         \
        acc[cf_][nf_] = __builtin_amdgcn_mfma_f32_16x16x32_bf16(Af[cf_][0], Bf[nf_][0], acc[cf_][nf_], 0, 0, 0); \
    _Pragma("unroll")                                                           \
    for (int cf_ = 0; cf_ < 4; ++cf_)                                           \
      _Pragma("unroll")                                                         \
      for (int nf_ = 0; nf_ < 2; ++nf_)                                         \
        acc[cf_][nf_] = __builtin_amdgcn_mfma_f32_16x16x32_bf16(Af[cf_][1], Bf[nf_][1], acc[cf_][nf_], 0, 0, 0); \
    __builtin_amdgcn_s_setprio(0);                                              \
    __builtin_amdgcn_s_barrier();                                               \
    if (DOSTAGE) PVSTAGE(CUR, ((kt) + 2) * 64);                                 \
  }

__global__ __launch_bounds__(512, 2) void pv(
    const float* __restrict__ x, const u16* __restrict__ Vb,
    const u16* __restrict__ P, const float* __restrict__ den,
    float* __restrict__ out)
{
    __shared__ u16 AS[2 * 8192];   // 2 bufs x 128rows x 64k  (V)  32 KB
    __shared__ u16 BS[2 * 8192];   // 2 bufs x 128rows x 64k  (P)  32 KB

    const int g = blockIdx.x;
    const int xcd = g & 7;
    const int b = xcd >> 1;
    const int idx = ((g >> 3) << 1) | (xcd & 1);  // 0..127 per batch
    const int bm = (idx >> 1) & 3;                // c-tile: sharers same XCD
    const int bn = ((idx >> 3) << 1) | (idx & 1); // n-tile 0..31

    const int tid = threadIdx.x;
    const int w = tid >> 6, l = tid & 63;
    const int lr = l & 15, lg = l >> 4;
    const int wr = w >> 2, wc = w & 3;            // wave: 64c x 32n

    const u16* Abase = Vb + (size_t)b * CIN * NTOK + (size_t)(bm * 128) * NTOK;
    const u16* Bbase = P + (size_t)b * NTOK * NTOK + (size_t)(bn * 128) * NTOK;

    f32x4 acc[4][2] = {};                         // [cf][nf]

    PVSTAGE(0, 0);
    PVSTAGE(1, 64);
    for (int kt2 = 0; kt2 < 62; kt2 += 2) {
        PVBODY(0, kt2 + 0, true, "4");
        PVBODY(1, kt2 + 1, true, "4");
    }
    PVBODY(0, 62, false, "4");
    PVBODY(1, 63, false, "0");

    // epilogue: out = x_t + acc / den[n]
    const float* denb = den + (size_t)b * NTOK;
    float inv[2];
    #pragma unroll
    for (int nf = 0; nf < 2; ++nf) inv[nf] = 1.0f / denb[bn * 128 + wc * 32 + nf * 16 + lr];

    const float* xtp = x + (size_t)(b + NBATCH) * CIN * NTOK;
    float* op = out + (size_t)(b + NBATCH) * CIN * NTOK;
    #pragma unroll
    for (int cf = 0; cf < 4; ++cf) {
        #pragma unroll
        for (int nf = 0; nf < 2; ++nf) {
            #pragma unroll
            for (int r = 0; r < 4; ++r) {
                const int c = bm * 128 + wr * 64 + cf * 16 + lg * 4 + r;
                const int n = bn * 128 + wc * 32 + nf * 16 + lr;
                const size_t idx2 = (size_t)c * NTOK + n;
                op[idx2] = xtp[idx2] + acc[cf][nf][r] * inv[nf];
            }
        }
    }
}

extern "C" void kernel_launch(void* const* d_in, const int* in_sizes, int n_in,
                              void* d_out, int out_size, void* d_ws, size_t ws_size,
                              hipStream_t stream)
{
    (void)in_sizes; (void)n_in; (void)out_size; (void)ws_size;
    const float* x  = (const float*)d_in[0];
    const float* Wq = (const float*)d_in[1];
    const float* bq = (const float*)d_in[2];
    const float* Wk = (const float*)d_in[3];
    const float* bk = (const float*)d_in[4];
    const float* Wv = (const float*)d_in[5];
    const float* bv = (const float*)d_in[6];
    float* out = (float*)d_out;

    // ws layout (~148.1 MB): Qh 2MB | Kf 2MB (fragment-order) | Vb 16MB |
    // den 64KB | P 128MB.  Wh (fragment-ordered f16 weights, 640KB) aliases
    // the head of P (dead before qk_exp writes P).
    u16* Qh = (u16*)d_ws;
    u16* Kf = Qh + (size_t)NBATCH * NTOK * OQK;
    u16* Vb = Kf + (size_t)NBATCH * NTOK * OQK;
    float* den = (float*)(Vb + (size_t)NBATCH * CIN * NTOK);
    u16* P  = (u16*)(den + (size_t)NBATCH * NTOK);
    u16* Wh = P;

    wcvt    <<<160, 256, 0, stream>>>(Wq, Wk, Wv, Wh);
    proj_all<<<dim3(128, NBATCH), 512, 0, stream>>>(x, bq, bk, bv, Wh, Qh, Kf, Vb, out);
    qk_exp  <<<1024, 256, 0, stream>>>(Qh, Kf, P, den);
    pv      <<<512, 512, 0, stream>>>(x, Vb, P, den, out);
}

// Round 22
// 156.876 us; speedup vs baseline: 1.4138x; 1.0055x over previous
//
#include <hip/hip_runtime.h>
#include <hip/hip_bf16.h>

#define CIN 512
#define OQK 64
#define NBATCH 4
#define NTOK 4096
#define L2E 1.44269504088896f

typedef float f32x4 __attribute__((ext_vector_type(4)));
typedef _Float16 f16x8 __attribute__((ext_vector_type(8)));
typedef short s16x8 __attribute__((ext_vector_type(8)));
typedef unsigned short u16;
typedef unsigned int u32;
typedef u32 u32x2 __attribute__((ext_vector_type(2)));
typedef u16 u16x4 __attribute__((ext_vector_type(4)));

__device__ inline u16 f2bf(float f) {
    unsigned u = __float_as_uint(f);
    u += 0x7fffu + ((u >> 16) & 1u);
    return (u16)(u >> 16);
}
__device__ inline u16 f2h_bits(float f) {
    _Float16 h = (_Float16)f;
    return __builtin_bit_cast(unsigned short, h);
}
// packed f32x2 -> bf16x2 (RTNE, same bits as f2bf) in ONE VALU op
__device__ inline u32 cvtpk_bf16(float lo, float hi) {
    u32 r;
    asm("v_cvt_pk_bf16_f32 %0, %1, %2" : "=v"(r) : "v"(lo), "v"(hi));
    return r;
}

// LDS-only barrier: does NOT drain vmcnt, so global stores/loads stay in
// flight across it (guide §6 G15 / r8 lesson; sched_barrier per rule #18).
#define LDS_BARRIER() { asm volatile("s_waitcnt lgkmcnt(0)" ::: "memory");      \
                        __builtin_amdgcn_s_barrier();                           \
                        __builtin_amdgcn_sched_barrier(0); }

#define GLOAD16(gp, lp) __builtin_amdgcn_global_load_lds(                        \
    (const __attribute__((address_space(1))) void*)(gp),                         \
    (__attribute__((address_space(3))) void*)(lp), 16, 0, 0)

// ---------------- W f32 -> f16 FRAGMENT-ORDER pre-convert (r20-verified) ----------------
// Wf[g][t][l][j] = W[g*16 + (l&15)][t*32 + (l>>4)*8 + j]
__global__ __launch_bounds__(256) void wcvt(
    const float* __restrict__ Wq, const float* __restrict__ Wk,
    const float* __restrict__ Wv, u16* __restrict__ Wh)
{
    const int tid = blockIdx.x * 256 + threadIdx.x;   // 0..40959 lane-fragments
    if (tid >= 40960) return;
    const float* src; u16* dst; int fi;
    if (tid < 4096)       { src = Wq; dst = Wh;         fi = tid; }
    else if (tid < 8192)  { src = Wk; dst = Wh + 32768; fi = tid - 4096; }
    else                  { src = Wv; dst = Wh + 65536; fi = tid - 8192; }
    const int l = fi & 63, gt = fi >> 6;
    const int t = gt & 15, g = gt >> 4;
    const int row = g * 16 + (l & 15);
    const int col = t * 32 + (l >> 4) * 8;
    const float* p = src + (size_t)row * CIN + col;
    f32x4 a = *reinterpret_cast<const f32x4*>(p);
    f32x4 b = *reinterpret_cast<const f32x4*>(p + 4);
    u16x4 h0, h1;
    #pragma unroll
    for (int j = 0; j < 4; ++j) { h0[j] = f2h_bits(a[j]); h1[j] = f2h_bits(b[j]); }
    *reinterpret_cast<u16x4*>(dst + (size_t)fi * 8)     = h0;
    *reinterpret_cast<u16x4*>(dst + (size_t)fi * 8 + 4) = h1;
}

// ---------------- fused Q/K/V projections + x_s passthrough ----------------
// r21-verified structure. NEW (r22): LDS-only barrier after staging -- the
// 16 x_s-copy stores per thread no longer serialize the block at the barrier.
__global__ __launch_bounds__(512, 4) void proj_all(
    const float* __restrict__ x,
    const float* __restrict__ bq, const float* __restrict__ bk, const float* __restrict__ bv,
    const u16* __restrict__ Wh,
    u16* __restrict__ Qh, u16* __restrict__ Kf, u16* __restrict__ Vb,
    float* __restrict__ out)
{
    __shared__ u16 Ls[32 * 520];
    __shared__ u16 Lt[32 * 520];

    const int nb = blockIdx.x;   // 128 panels of 32 tokens
    const int b  = blockIdx.y;   // 4
    const int tid = threadIdx.x;
    const int w = tid >> 6, l = tid & 63;
    const int lr = l & 15, lg = l >> 4;
    const int n0 = nb * 32;

    const float* xs = x + (size_t)b * CIN * NTOK;
    const float* xt = x + (size_t)(b + NBATCH) * CIN * NTOK;
    float* os = out + (size_t)b * CIN * NTOK;

    // ---- stage both panels (threads 0-255: x_s + out copy; 256-511: x_t) ----
    {
        const int sg = tid >> 8, st = tid & 255;
        const int q = st & 7, cpb = st >> 3;     // n-quad, channel-pair base
        const float* src = sg ? xt : xs;
        u16* Lp = sg ? Lt : Ls;
        #pragma unroll
        for (int r = 0; r < 8; ++r) {
            const int c0 = (cpb + r * 32) * 2;
            f32x4 va = *reinterpret_cast<const f32x4*>(src + (size_t)c0 * NTOK + n0 + q * 4);
            f32x4 vb = *reinterpret_cast<const f32x4*>(src + (size_t)(c0 + 1) * NTOK + n0 + q * 4);
            if (!sg) {
                *reinterpret_cast<f32x4*>(os + (size_t)c0 * NTOK + n0 + q * 4) = va;
                *reinterpret_cast<f32x4*>(os + (size_t)(c0 + 1) * NTOK + n0 + q * 4) = vb;
            }
            #pragma unroll
            for (int j = 0; j < 4; ++j) {
                u32 pk = (u32)f2h_bits(va[j]) | ((u32)f2h_bits(vb[j]) << 16);
                *reinterpret_cast<u32*>(&Lp[(q * 4 + j) * 520 + c0]) = pk;
            }
        }
    }
    LDS_BARRIER();   // r22: LDS-only -- x_s copy stores stay in flight

    const u16* Wqf = Wh;
    const u16* Wkf = Wh + 32768;
    const u16* Wvf = Wh + 65536;
    const bool isq = (w < 4);
    const int h  = isq ? (w >> 1) : 0;            // Q: token-half
    const int ob = isq ? ((w & 1) * 2) : (w - 4); // Q: o-pair base; K: o-quarter

    f32x4 macc[4][2] = {};   // V accum [cf][fm]  (D[m][c] orientation)
    f32x4 xacc[2] = {};      // Q (i) or K (h2)   (D[o][n] orientation)

    #pragma unroll 4
    for (int t = 0; t < 16; ++t) {
        const int c0 = t * 32 + lg * 8;
        f16x8 X0 = *reinterpret_cast<const f16x8*>(&Lt[lr * 520 + c0]);
        f16x8 X1 = *reinterpret_cast<const f16x8*>(&Lt[(16 + lr) * 520 + c0]);
        #pragma unroll
        for (int cf = 0; cf < 4; ++cf) {
            f16x8 Wvv = *reinterpret_cast<const f16x8*>(&Wvf[(size_t)(((w * 4 + cf) * 16 + t) * 64 + l) * 8]);
            macc[cf][0] = __builtin_amdgcn_mfma_f32_16x16x32_f16(X0, Wvv, macc[cf][0], 0, 0, 0);
            macc[cf][1] = __builtin_amdgcn_mfma_f32_16x16x32_f16(X1, Wvv, macc[cf][1], 0, 0, 0);
        }
        if (isq) {
            f16x8 Xs = *reinterpret_cast<const f16x8*>(&Ls[(h * 16 + lr) * 520 + c0]);
            #pragma unroll
            for (int i = 0; i < 2; ++i) {
                f16x8 Wqv = *reinterpret_cast<const f16x8*>(&Wqf[(size_t)((((ob + i) * 16) + t) * 64 + l) * 8]);
                xacc[i] = __builtin_amdgcn_mfma_f32_16x16x32_f16(Wqv, Xs, xacc[i], 0, 0, 0);
            }
        } else {
            f16x8 Wkv = *reinterpret_cast<const f16x8*>(&Wkf[(size_t)((ob * 16 + t) * 64 + l) * 8]);
            xacc[0] = __builtin_amdgcn_mfma_f32_16x16x32_f16(Wkv, X0, xacc[0], 0, 0, 0);
            xacc[1] = __builtin_amdgcn_mfma_f32_16x16x32_f16(Wkv, X1, xacc[1], 0, 0, 0);
        }
    }

    // ---- V store: packed bf16x4 along m (cvt_pk) ----
    #pragma unroll
    for (int cf = 0; cf < 4; ++cf) {
        const int c = w * 64 + cf * 16 + lr;
        const float bvc = bv[c];
        #pragma unroll
        for (int fm = 0; fm < 2; ++fm) {
            u32x2 pk;
            pk[0] = cvtpk_bf16(macc[cf][fm][0] + bvc, macc[cf][fm][1] + bvc);
            pk[1] = cvtpk_bf16(macc[cf][fm][2] + bvc, macc[cf][fm][3] + bvc);
            *reinterpret_cast<u32x2*>(&Vb[((size_t)b * CIN + c) * NTOK + n0 + fm * 16 + lg * 4]) = pk;
        }
    }
    // ---- Q store: packed f16x4 along o (row-major), Q scaled by log2(e) ----
    if (isq) {
        #pragma unroll
        for (int i = 0; i < 2; ++i) {
            u16x4 pk;
            #pragma unroll
            for (int r = 0; r < 4; ++r)
                pk[r] = f2h_bits((xacc[i][r] + bq[(ob + i) * 16 + lg * 4 + r]) * L2E);
            *reinterpret_cast<u16x4*>(&Qh[((size_t)b * NTOK + n0 + h * 16 + lr) * OQK + (ob + i) * 16 + lg * 4]) = pk;
        }
    } else {
        // ---- K store: FRAGMENT ORDER (r21-verified) ----
        const int lanep = lr + ((ob & 1) * 2 + (lg >> 1)) * 16;
        #pragma unroll
        for (int h2 = 0; h2 < 2; ++h2) {
            u16x4 pk;
            #pragma unroll
            for (int r = 0; r < 4; ++r) pk[r] = f2h_bits(xacc[h2][r] + bk[ob * 16 + lg * 4 + r]);
            u16* dst = Kf + (((size_t)b * 256 + nb * 2 + h2) * 2 + (ob >> 1)) * 512
                          + lanep * 8 + (lg & 1) * 4;
            *reinterpret_cast<u16x4*>(dst) = pk;
        }
    }
}

// ---------------- pass S: P = exp2(K Q'^T) (bf16) + exact den ----------------
// r21-verified core (fragment-ordered K loads). NEW (r22): final barrier is
// LDS-only so the P-store queue is not drained before the den write.

#define SLOADK(mt, KF)                                                          \
  { _Pragma("unroll")                                                           \
    for (int mf_ = 0; mf_ < 4; ++mf_) {                                         \
      _Pragma("unroll")                                                         \
      for (int kk_ = 0; kk_ < 2; ++kk_)                                         \
        KF[mf_][kk_] = *reinterpret_cast<const f16x8*>(                         \
            &Kfrag[(((size_t)(w * 64 + (mt) * 4 + mf_)) * 2 + kk_) * 512 + l * 8]); \
    } }

#define STILE(mt, KF)                                                           \
  { _Pragma("unroll")                                                           \
    for (int mf_ = 0; mf_ < 4; ++mf_) {                                         \
      f32x4 s_ = {};                                                            \
      s_ = __builtin_amdgcn_mfma_f32_16x16x32_f16(KF[mf_][0], Bq0, s_, 0, 0, 0);\
      s_ = __builtin_amdgcn_mfma_f32_16x16x32_f16(KF[mf_][1], Bq1, s_, 0, 0, 0);\
      float p0 = exp2f(s_[0]), p1 = exp2f(s_[1]);                               \
      float p2 = exp2f(s_[2]), p3 = exp2f(s_[3]);                               \
      denl += (p0 + p1) + (p2 + p3);                                            \
      u32x2 pk;                                                                 \
      pk[0] = cvtpk_bf16(p0, p1);                                               \
      pk[1] = cvtpk_bf16(p2, p3);                                               \
      const int widx_ = (lr * 64 + mf_ * 16 + lg * 4) ^ ((lr & 7) << 3);        \
      *reinterpret_cast<u32x2*>(&Tw[widx_]) = pk;                               \
    }                                                                           \
    _Pragma("unroll")                                                           \
    for (int rr_ = 0; rr_ < 2; ++rr_) {                                         \
      const int nl_ = (l >> 3) + rr_ * 8;                                       \
      const int ridx_ = (nl_ * 64 + (l & 7) * 8) ^ ((nl_ & 7) << 3);            \
      s16x8 v_ = *reinterpret_cast<const s16x8*>(&Tw[ridx_]);                   \
      *reinterpret_cast<s16x8*>(&Pp[(size_t)(grp * 16 + nl_) * NTOK + (mt) * 64 + (l & 7) * 8]) = v_; \
    } }

__global__ __launch_bounds__(256, 4) void qk_exp(
    const u16* __restrict__ Qh, const u16* __restrict__ Kf,
    u16* __restrict__ P, float* __restrict__ den)
{
    __shared__ float dpart[4][16];
    __shared__ u16 T[4][1024];                     // per-wave 16x64 transpose tile
    const int g = blockIdx.x;
    const int xcd = g & 7;
    const int b = xcd >> 1;
    const int grp = ((g >> 3) << 1) | (xcd & 1);   // 16-row group (0..255)

    const int tid = threadIdx.x;
    const int w = tid >> 6, l = tid & 63;
    const int lr = l & 15, lg = l >> 4;

    const int n = grp * 16 + lr;
    const int mbase = w * 1024;                    // wave's m-quarter
    const u16* Kfrag = Kf + (size_t)b * 256 * 2 * 512;
    u16* Pp = P + (size_t)b * NTOK * NTOK + mbase;
    u16* Tw = T[w];

    f16x8 Bq0, Bq1;
    {
        const u16* qp = Qh + ((size_t)b * NTOK + n) * OQK + lg * 8;
        Bq0 = *reinterpret_cast<const f16x8*>(qp);
        Bq1 = *reinterpret_cast<const f16x8*>(qp + 32);
    }

    float denl = 0.f;
    f16x8 KfA[4][2], KfB[4][2];

    SLOADK(0, KfA);
    for (int mt = 0; mt < 16; mt += 2) {
        SLOADK(mt + 1, KfB);
        STILE(mt, KfA);
        if (mt + 2 < 16) SLOADK(mt + 2, KfA);
        STILE(mt + 1, KfB);
    }

    denl += __shfl_xor(denl, 16);
    denl += __shfl_xor(denl, 32);
    if (l < 16) dpart[w][l] = denl;
    LDS_BARRIER();   // r22: LDS-only -- P stores stay in flight
    if (tid < 16)
        den[(size_t)b * NTOK + grp * 16 + tid] =
            (dpart[0][tid] + dpart[1][tid]) + (dpart[2][tid] + dpart[3][tid]);
}

// ---------------- pass PV: out = x_t + (V P^T) / den (r19-verified, ~79 us) ----------------
// BK=64, 64 K-tiles, 512 thr (8 waves, wave = 64c x 32n). 2 bufs x 32KB = 64KB
// LDS -> 2 blocks/CU = 16 waves/CU. Stage(kt+2) after 2nd barrier; steady
// vmcnt(4), tail 4/0. Swizzle: slot ^= row&7. XCD P-sharing map (r14).

#define PVSTAGE(BUF, m0)                                                        \
  { _Pragma("unroll")                                                           \
    for (int i_ = 0; i_ < 2; ++i_) {                                            \
      const int chunk_ = i_ * 512 + tid;                                        \
      const int row_ = chunk_ >> 3;                                             \
      const int sl_ = (chunk_ & 7) ^ (row_ & 7);                                \
      GLOAD16(Abase + (size_t)row_ * NTOK + (m0) + sl_ * 8,                     \
              &AS[(BUF) * 8192 + chunk_ * 8]);                                  \
    }                                                                           \
    _Pragma("unroll")                                                           \
    for (int j_ = 0; j_ < 2; ++j_) {                                            \
      const int chunk_ = j_ * 512 + tid;                                        \
      const int row_ = chunk_ >> 3;                                             \
      const int sl_ = (chunk_ & 7) ^ (row_ & 7);                                \
      GLOAD16(Bbase + (size_t)row_ * NTOK + (m0) + sl_ * 8,                     \
              &BS[(BUF) * 8192 + chunk_ * 8]);                                  \
    } }

#define PVBODY(CUR, kt, DOSTAGE, VM)                                            \
  {                                                                             \
    asm volatile("s_waitcnt vmcnt(" VM ")" ::: "memory");                       \
    __builtin_amdgcn_s_barrier();                                               \
    s16x8 Af[4][2], Bf[2][2];                                                   \
    _Pragma("unroll")                                                           \
    for (int cf_ = 0; cf_ < 4; ++cf_) {                                         \
      const int r_ = wr * 64 + cf_ * 16 + lr;                                   \
      _Pragma("unroll")                                                         \
      for (int kk_ = 0; kk_ < 2; ++kk_) {                                       \
        const int s_ = (kk_ * 4 + lg) ^ (r_ & 7);                               \
        Af[cf_][kk_] = *(const s16x8*)&AS[(CUR) * 8192 + r_ * 64 + s_ * 8];     \
      } }                                                                       \
    _Pragma("unroll")                                                           \
    for (int nf_ = 0; nf_ < 2; ++nf_) {                                         \
      const int r_ = wc * 32 + nf_ * 16 + lr;                                   \
      _Pragma("unroll")                                                         \
      for (int kk_ = 0; kk_ < 2; ++kk_) {                                       \
        const int s_ = (kk_ * 4 + lg) ^ (r_ & 7);                               \
        Bf[nf_][kk_] = *(const s16x8*)&BS[(CUR) * 8192 + r_ * 64 + s_ * 8];     \
      } }                                                                       \
    __builtin_amdgcn_s_setprio(1);                                              \
    _Pragma("unroll")                                                           \
    for (int cf_ = 0; cf_ < 4; ++cf_)                                           \
      _Pragma("unroll")                                                         \
      for (int nf_ = 0; nf_ < 2; ++nf_)                                         \
        acc[cf_][nf_] = __builtin_amdgcn_mfma_f32_16x16x32_bf16(Af[cf_][0], Bf[nf_][0], acc[cf_][nf_], 0, 0, 0); \
    _Pragma("unroll")                                                           \
    for (int cf_ = 0; cf_ < 4; ++cf_)                                           \
      _Pragma("unroll")                                                         \
      for (int nf_ = 0; nf_ < 2; ++nf_)                                         \
        acc[cf_][nf_] = __builtin_amdgcn_mfma_f32_16x16x32_bf16(Af[cf_][1], Bf[nf_][1], acc[cf_][nf_], 0, 0, 0); \
    __builtin_amdgcn_s_setprio(0);                                              \
    __builtin_amdgcn_s_barrier();                                               \
    if (DOSTAGE) PVSTAGE(CUR, ((kt) + 2) * 64);                                 \
  }

__global__ __launch_bounds__(512, 2) void pv(
    const float* __restrict__ x, const u16* __restrict__ Vb,
    const u16* __restrict__ P, const float* __restrict__ den,
    float* __restrict__ out)
{
    __shared__ u16 AS[2 * 8192];   // 2 bufs x 128rows x 64k  (V)  32 KB
    __shared__ u16 BS[2 * 8192];   // 2 bufs x 128rows x 64k  (P)  32 KB

    const int g = blockIdx.x;
    const int xcd = g & 7;
    const int b = xcd >> 1;
    const int idx = ((g >> 3) << 1) | (xcd & 1);  // 0..127 per batch
    const int bm = (idx >> 1) & 3;                // c-tile: sharers same XCD
    const int bn = ((idx >> 3) << 1) | (idx & 1); // n-tile 0..31

    const int tid = threadIdx.x;
    const int w = tid >> 6, l = tid & 63;
    const int lr = l & 15, lg = l >> 4;
    const int wr = w >> 2, wc = w & 3;            // wave: 64c x 32n

    const u16* Abase = Vb + (size_t)b * CIN * NTOK + (size_t)(bm * 128) * NTOK;
    const u16* Bbase = P + (size_t)b * NTOK * NTOK + (size_t)(bn * 128) * NTOK;

    f32x4 acc[4][2] = {};                         // [cf][nf]

    PVSTAGE(0, 0);
    PVSTAGE(1, 64);
    for (int kt2 = 0; kt2 < 62; kt2 += 2) {
        PVBODY(0, kt2 + 0, true, "4");
        PVBODY(1, kt2 + 1, true, "4");
    }
    PVBODY(0, 62, false, "4");
    PVBODY(1, 63, false, "0");

    // epilogue: out = x_t + acc / den[n]
    const float* denb = den + (size_t)b * NTOK;
    float inv[2];
    #pragma unroll
    for (int nf = 0; nf < 2; ++nf) inv[nf] = 1.0f / denb[bn * 128 + wc * 32 + nf * 16 + lr];

    const float* xtp = x + (size_t)(b + NBATCH) * CIN * NTOK;
    float* op = out + (size_t)(b + NBATCH) * CIN * NTOK;
    #pragma unroll
    for (int cf = 0; cf < 4; ++cf) {
        #pragma unroll
        for (int nf = 0; nf < 2; ++nf) {
            #pragma unroll
            for (int r = 0; r < 4; ++r) {
                const int c = bm * 128 + wr * 64 + cf * 16 + lg * 4 + r;
                const int n = bn * 128 + wc * 32 + nf * 16 + lr;
                const size_t idx2 = (size_t)c * NTOK + n;
                op[idx2] = xtp[idx2] + acc[cf][nf][r] * inv[nf];
            }
        }
    }
}

extern "C" void kernel_launch(void* const* d_in, const int* in_sizes, int n_in,
                              void* d_out, int out_size, void* d_ws, size_t ws_size,
                              hipStream_t stream)
{
    (void)in_sizes; (void)n_in; (void)out_size; (void)ws_size;
    const float* x  = (const float*)d_in[0];
    const float* Wq = (const float*)d_in[1];
    const float* bq = (const float*)d_in[2];
    const float* Wk = (const float*)d_in[3];
    const float* bk = (const float*)d_in[4];
    const float* Wv = (const float*)d_in[5];
    const float* bv = (const float*)d_in[6];
    float* out = (float*)d_out;

    // ws layout (~148.1 MB): Qh 2MB | Kf 2MB (fragment-order) | Vb 16MB |
    // den 64KB | P 128MB.  Wh (fragment-ordered f16 weights, 640KB) aliases
    // the head of P (dead before qk_exp writes P).
    u16* Qh = (u16*)d_ws;
    u16* Kf = Qh + (size_t)NBATCH * NTOK * OQK;
    u16* Vb = Kf + (size_t)NBATCH * NTOK * OQK;
    float* den = (float*)(Vb + (size_t)NBATCH * CIN * NTOK);
    u16* P  = (u16*)(den + (size_t)NBATCH * NTOK);
    u16* Wh = P;

    wcvt    <<<160, 256, 0, stream>>>(Wq, Wk, Wv, Wh);
    proj_all<<<dim3(128, NBATCH), 512, 0, stream>>>(x, bq, bk, bv, Wh, Qh, Kf, Vb, out);
    qk_exp  <<<1024, 256, 0, stream>>>(Qh, Kf, P, den);
    pv      <<<512, 512, 0, stream>>>(x, Vb, P, den, out);
}